// Round 4
// baseline (235.161 us; speedup 1.0000x reference)
//
#include <hip/hip_runtime.h>
#include <hip/hip_bf16.h>
#include <math.h>

#define N_NODES 20000
#define MPAD 20096               // 157*128
#define N_EDGES 320000
#define EP (N_EDGES + N_NODES)   // 340000
#define F_IN 256
#define NHID 64
#define H1 8
#define D1 512
#define NCLS 40
#define NEG_SLOPE 0.2f
#define MAXD 128                 // LDS-cached edges per dst; deg~Poisson(17), P(deg>128)~0

typedef __attribute__((ext_vector_type(8))) short bf16x8;
typedef __attribute__((ext_vector_type(4))) float f32x4;

__device__ __forceinline__ float wave_max(float v) {
#pragma unroll
  for (int o = 32; o > 0; o >>= 1) v = fmaxf(v, __shfl_xor(v, o));
  return v;
}
__device__ __forceinline__ float wave_sum(float v) {
#pragma unroll
  for (int o = 32; o > 0; o >>= 1) v += __shfl_xor(v, o);
  return v;
}
__device__ __forceinline__ float bf2f(unsigned short u) {
  union { unsigned int i; float f; } c; c.i = ((unsigned int)u) << 16; return c.f;
}
__device__ __forceinline__ unsigned short f2bf(float f) {
  union { float f; unsigned int i; } c; c.f = f;
  unsigned int x = c.i;
  return (unsigned short)((x + 0x7fffu + ((x >> 16) & 1u)) >> 16);  // RNE
}
__device__ __forceinline__ float asf(unsigned int u) {
  union { unsigned int i; float f; } c; c.i = u; return c.f;
}
__device__ __forceinline__ float lrelu(float x) { return x > 0.f ? x : NEG_SLOPE * x; }

// async global->LDS, 16B per lane; LDS dest = wave-uniform base + lane*16
__device__ __forceinline__ void gload16(const void* g, void* l) {
  __builtin_amdgcn_global_load_lds((const __attribute__((address_space(1))) void*)g,
                                   (__attribute__((address_space(3))) void*)l, 16, 0, 0);
}

// ---------------- CSR build ----------------
__global__ void count_deg(const int* __restrict__ ei, int* __restrict__ deg) {
  int e = blockIdx.x * blockDim.x + threadIdx.x;
  if (e >= EP) return;
  int dst = (e < N_EDGES) ? ei[N_EDGES + e] : (e - N_EDGES);
  atomicAdd(&deg[dst], 1);
}

#define SCAN_T 256
#define SCAN_CHUNK 79
__global__ void scan_kernel(const int* __restrict__ deg, int* __restrict__ offsets) {
  __shared__ int sums[SCAN_T];
  int t = threadIdx.x;
  int lo = t * SCAN_CHUNK;
  int hi = min(lo + SCAN_CHUNK, N_NODES);
  int s = 0;
  for (int i = lo; i < hi; ++i) s += deg[i];
  sums[t] = s;
  __syncthreads();
  if (t == 0) {
    int run = 0;
    for (int i = 0; i < SCAN_T; ++i) { int v = sums[i]; sums[i] = run; run += v; }
  }
  __syncthreads();
  int run = sums[t];
  for (int i = lo; i < hi; ++i) { offsets[i] = run; run += deg[i]; }
  if (hi == N_NODES) offsets[N_NODES] = run;
}

__global__ void scatter_edges(const int* __restrict__ ei, const int* __restrict__ offsets,
                              int* __restrict__ cursor, int* __restrict__ edge_src) {
  int e = blockIdx.x * blockDim.x + threadIdx.x;
  if (e >= EP) return;
  int src, dst;
  if (e < N_EDGES) { src = ei[e]; dst = ei[N_EDGES + e]; }
  else             { src = dst = e - N_EDGES; }
  int pos = offsets[dst] + atomicAdd(&cursor[dst], 1);
  edge_src[pos] = src;
}

// ---------------- converts ----------------
__global__ void convert_x(const float* __restrict__ x, unsigned short* __restrict__ xb) {
  size_t base = ((size_t)blockIdx.x * blockDim.x + threadIdx.x) * 8;
  int row = (int)(base >> 8);
  ushort4 o0, o1;
  if (row < N_NODES) {
    float4 v0 = *(const float4*)&x[base];
    float4 v1 = *(const float4*)&x[base + 4];
    o0 = make_ushort4(f2bf(v0.x), f2bf(v0.y), f2bf(v0.z), f2bf(v0.w));
    o1 = make_ushort4(f2bf(v1.x), f2bf(v1.y), f2bf(v1.z), f2bf(v1.w));
  } else {
    o0 = make_ushort4(0, 0, 0, 0); o1 = o0;
  }
  *(ushort4*)&xb[base] = o0;
  *(ushort4*)&xb[base + 4] = o1;
}

// W1 [256][512] f32 -> wb1t [512][256] bf16 (transposed)
__global__ __launch_bounds__(256) void transpose_w1(const float* __restrict__ W1,
                                                    unsigned short* __restrict__ wb1t) {
  __shared__ float t[64][65];
  int bk = blockIdx.x & 3, bn = blockIdx.x >> 2;
  int tr = threadIdx.x >> 4, tc4 = (threadIdx.x & 15) * 4;
#pragma unroll
  for (int i = 0; i < 4; ++i) {
    int k = i * 16 + tr;
    float4 v = *(const float4*)&W1[(size_t)(bk * 64 + k) * D1 + bn * 64 + tc4];
    t[k][tc4] = v.x; t[k][tc4 + 1] = v.y; t[k][tc4 + 2] = v.z; t[k][tc4 + 3] = v.w;
  }
  __syncthreads();
#pragma unroll
  for (int i = 0; i < 4; ++i) {
    int n = i * 16 + tr;
    ushort4 o = make_ushort4(f2bf(t[tc4][n]), f2bf(t[tc4 + 1][n]),
                             f2bf(t[tc4 + 2][n]), f2bf(t[tc4 + 3][n]));
    *(ushort4*)&wb1t[(size_t)(bn * 64 + n) * F_IN + bk * 64 + tc4] = o;
  }
}

// W2 [512][40] f32 -> wb2t [48][512] bf16 (transposed, zero-padded cols 40..47)
__global__ void transpose_w2(const float* __restrict__ W2, unsigned short* __restrict__ wb2t) {
  int c = blockIdx.x;   // 0..47
  int k = threadIdx.x;  // 0..511
  float v = (c < NCLS) ? W2[(size_t)k * NCLS + c] : 0.f;
  wb2t[(size_t)c * D1 + k] = f2bf(v);
}

// ---------------- GEMM1 (MFMA): h1b = xb @ W1, fused alpha1 ----------------
__global__ __launch_bounds__(256) void gemm1_mfma(const unsigned short* __restrict__ xb,
                                                  const unsigned short* __restrict__ wb1t,
                                                  const float* __restrict__ a_src,
                                                  const float* __restrict__ a_dst,
                                                  unsigned short* __restrict__ h1b,
                                                  float* __restrict__ asrc,
                                                  float* __restrict__ adst) {
  __shared__ unsigned short As[128 * 32];
  __shared__ unsigned short Bs[128 * 32];
  int tid = threadIdx.x;
  int w = tid >> 6, lane = tid & 63;
  int bn = blockIdx.x & 3, bm = blockIdx.x >> 2;
  int row0 = bm * 128, col0 = bn * 128;
  int wr = w >> 1, wc = w & 1;
  int cl = lane & 15, hi = lane >> 4;
  f32x4 acc[4][4] = {};
  for (int k0 = 0; k0 < F_IN; k0 += 32) {
#pragma unroll
    for (int c = 0; c < 2; ++c) {
      int slot = c * 256 + tid;
      int r = slot >> 2;
      int q = (slot & 3) ^ ((slot >> 3) & 3);   // pre-swizzled source (rule 21)
      gload16(xb + (size_t)(row0 + r) * F_IN + k0 + q * 8, (char*)As + (c * 256 + w * 64) * 16);
      gload16(wb1t + (size_t)(col0 + r) * F_IN + k0 + q * 8, (char*)Bs + (c * 256 + w * 64) * 16);
    }
    __syncthreads();
    bf16x8 a[4], b[4];
#pragma unroll
    for (int m = 0; m < 4; ++m) {
      int r = wr * 64 + m * 16 + cl;
      a[m] = *(const bf16x8*)&As[r * 32 + ((hi ^ ((r >> 1) & 3)) << 3)];
    }
#pragma unroll
    for (int n = 0; n < 4; ++n) {
      int r = wc * 64 + n * 16 + cl;
      b[n] = *(const bf16x8*)&Bs[r * 32 + ((hi ^ ((r >> 1) & 3)) << 3)];
    }
#pragma unroll
    for (int m = 0; m < 4; ++m)
#pragma unroll
      for (int n = 0; n < 4; ++n)
        acc[m][n] = __builtin_amdgcn_mfma_f32_16x16x32_bf16(a[m], b[n], acc[m][n], 0, 0, 0);
    __syncthreads();
  }
  int head = bn * 2 + wc;
  float asv[4], adv[4];
#pragma unroll
  for (int n = 0; n < 4; ++n) {
    asv[n] = a_src[head * 64 + n * 16 + cl];
    adv[n] = a_dst[head * 64 + n * 16 + cl];
  }
#pragma unroll
  for (int m = 0; m < 4; ++m) {
#pragma unroll
    for (int r = 0; r < 4; ++r) {
      int grow = row0 + wr * 64 + m * 16 + hi * 4 + r;
      float ps = acc[m][0][r] * asv[0] + acc[m][1][r] * asv[1] +
                 acc[m][2][r] * asv[2] + acc[m][3][r] * asv[3];
      float pd = acc[m][0][r] * adv[0] + acc[m][1][r] * adv[1] +
                 acc[m][2][r] * adv[2] + acc[m][3][r] * adv[3];
#pragma unroll
      for (int o = 8; o > 0; o >>= 1) { ps += __shfl_xor(ps, o); pd += __shfl_xor(pd, o); }
      if (grow < N_NODES) {
#pragma unroll
        for (int n = 0; n < 4; ++n)
          h1b[(size_t)grow * D1 + col0 + wc * 64 + n * 16 + cl] = f2bf(acc[m][n][r]);
        if (cl == 0) { asrc[grow * H1 + head] = ps; adst[grow * H1 + head] = pd; }
      }
    }
  }
}

// ---------------- agg1: LDS alpha + 16B bf16 gather (8 edges/iter) + b1 + ELU ----------------
__global__ __launch_bounds__(512) void agg1_kernel(const int* __restrict__ offsets,
                                                   const int* __restrict__ edge_src,
                                                   const float* __restrict__ asrc,
                                                   const float* __restrict__ adst,
                                                   const unsigned short* __restrict__ h1b,
                                                   const float* __restrict__ b1,
                                                   unsigned short* __restrict__ out1b) {
  __shared__ float lalpha[H1][MAXD];
  __shared__ int   lsoff[MAXD];
  int n = blockIdx.x;
  int h = threadIdx.x >> 6;
  int lane = threadIdx.x & 63;
  int base = offsets[n];
  int deg = offsets[n + 1] - base;
  int degc = min(deg, MAXD);
  int degp = (degc + 7) & ~7;   // pad to 8

  // phase 0: src byte-offsets (row stride 1024B), zero-pad
  for (int e = (int)threadIdx.x; e < degp; e += 512)
    lsoff[e] = (e < degc) ? (edge_src[base + e] << 10) : 0;
  __syncthreads();

  float advv = adst[n * H1 + h];
  // pass A: logits -> LDS, max
  float m = -INFINITY;
  for (int e = lane; e < deg; e += 64) {
    int s = (e < MAXD) ? (lsoff[e] >> 10) : edge_src[base + e];
    float ev = lrelu(asrc[s * H1 + h] + advv);
    if (e < MAXD) lalpha[h][e] = ev;
    m = fmaxf(m, ev);
  }
  m = wave_max(m);
  // pass B: sum exp
  float ssum = 0.f;
  for (int e = lane; e < deg; e += 64) {
    float ev;
    if (e < MAXD) ev = lalpha[h][e];
    else { int s = edge_src[base + e]; ev = lrelu(asrc[s * H1 + h] + advv); }
    ssum += __expf(ev - m);
  }
  float inv = 1.f / (wave_sum(ssum) + 1e-16f);
  // pass C: normalized alpha, zero-pad
  for (int e = lane; e < degc; e += 64) lalpha[h][e] = __expf(lalpha[h][e] - m) * inv;
  {
    int e = degc + lane;
    if (e < degp) lalpha[h][e] = 0.f;
  }
  // no extra sync: lalpha[h] is produced & consumed by the same wave; lsoff synced above

  // heavy loop: 8 edges/iter, 16B (8 ch) per lane
  int esub = lane >> 3;         // edge sub-slot 0..7
  int cg = lane & 7;            // channel group (8 ch = 16B)
  const char* hb = (const char*)h1b + h * 128 + cg * 16;
  float acc[8] = {};
  for (int i = 0; i < degp; i += 8) {
    int slot = i + esub;
    float a = lalpha[h][slot];
    int so = lsoff[slot];
    uint4 uv = *(const uint4*)(hb + so);
#pragma unroll
    for (int j = 0; j < 4; ++j) {
      unsigned int u = ((const unsigned int*)&uv)[j];
      acc[2 * j]     += a * asf(u << 16);
      acc[2 * j + 1] += a * asf(u & 0xffff0000u);
    }
  }
  // fallback deg > MAXD (never runs for this graph; correctness guard)
  for (int e = MAXD + esub; e < deg; e += 8) {
    int s = edge_src[base + e];
    float a = __expf(lrelu(asrc[s * H1 + h] + advv) - m) * inv;
    uint4 uv = *(const uint4*)(hb + ((size_t)s << 10));
#pragma unroll
    for (int j = 0; j < 4; ++j) {
      unsigned int u = ((const unsigned int*)&uv)[j];
      acc[2 * j]     += a * asf(u << 16);
      acc[2 * j + 1] += a * asf(u & 0xffff0000u);
    }
  }
  // reduce across the 8 edge sub-slots (lanes cg, cg+8, ..., cg+56)
#pragma unroll
  for (int j = 0; j < 8; ++j) {
    acc[j] += __shfl_xor(acc[j], 8);
    acc[j] += __shfl_xor(acc[j], 16);
    acc[j] += __shfl_xor(acc[j], 32);
  }
  if (lane < 8) {               // lane == cg, esub == 0
    int c0 = h * NHID + lane * 8;
    ushort4 o0, o1;
    float v[8];
#pragma unroll
    for (int j = 0; j < 8; ++j) {
      float t = acc[j] + b1[c0 + j];
      v[j] = t > 0.f ? t : (__expf(t) - 1.f);   // ELU
    }
    o0 = make_ushort4(f2bf(v[0]), f2bf(v[1]), f2bf(v[2]), f2bf(v[3]));
    o1 = make_ushort4(f2bf(v[4]), f2bf(v[5]), f2bf(v[6]), f2bf(v[7]));
    *(ushort4*)&out1b[(size_t)n * D1 + c0] = o0;
    *(ushort4*)&out1b[(size_t)n * D1 + c0 + 4] = o1;
  }
}

// ---------------- GEMM2 (MFMA): h2 = out1b @ W2 (+pad), fused alpha2 ----------------
__global__ __launch_bounds__(256) void gemm2_mfma(const unsigned short* __restrict__ ab,
                                                  const unsigned short* __restrict__ wb2t,
                                                  const float* __restrict__ a_src2,
                                                  const float* __restrict__ a_dst2,
                                                  float* __restrict__ h2,
                                                  float* __restrict__ asrc,
                                                  float* __restrict__ adst) {
  __shared__ unsigned short As[128 * 32];
  __shared__ unsigned short Bs[48 * 32];
  int tid = threadIdx.x;
  int w = tid >> 6, lane = tid & 63;
  int row0 = blockIdx.x * 128;
  int cl = lane & 15, hi = lane >> 4;
  f32x4 acc[2][3] = {};
  for (int k0 = 0; k0 < D1; k0 += 32) {
#pragma unroll
    for (int c = 0; c < 2; ++c) {
      int slot = c * 256 + tid;
      int r = slot >> 2;
      int q = (slot & 3) ^ ((slot >> 3) & 3);
      gload16(ab + (size_t)(row0 + r) * D1 + k0 + q * 8, (char*)As + (c * 256 + w * 64) * 16);
    }
    if (tid < 192) {
      int r = tid >> 2;
      int q = (tid & 3) ^ ((tid >> 3) & 3);
      gload16(wb2t + (size_t)r * D1 + k0 + q * 8, (char*)Bs + w * 64 * 16);
    }
    __syncthreads();
    bf16x8 a[2], b[3];
#pragma unroll
    for (int m = 0; m < 2; ++m) {
      int r = w * 32 + m * 16 + cl;
      a[m] = *(const bf16x8*)&As[r * 32 + ((hi ^ ((r >> 1) & 3)) << 3)];
    }
#pragma unroll
    for (int n = 0; n < 3; ++n) {
      int r = n * 16 + cl;
      b[n] = *(const bf16x8*)&Bs[r * 32 + ((hi ^ ((r >> 1) & 3)) << 3)];
    }
#pragma unroll
    for (int m = 0; m < 2; ++m)
#pragma unroll
      for (int n = 0; n < 3; ++n)
        acc[m][n] = __builtin_amdgcn_mfma_f32_16x16x32_bf16(a[m], b[n], acc[m][n], 0, 0, 0);
    __syncthreads();
  }
  float asv[3], adv[3];
#pragma unroll
  for (int n = 0; n < 3; ++n) {
    int c = n * 16 + cl;
    asv[n] = (c < NCLS) ? a_src2[c] : 0.f;
    adv[n] = (c < NCLS) ? a_dst2[c] : 0.f;
  }
#pragma unroll
  for (int m = 0; m < 2; ++m) {
#pragma unroll
    for (int r = 0; r < 4; ++r) {
      int grow = row0 + w * 32 + m * 16 + hi * 4 + r;
      float ps = acc[m][0][r] * asv[0] + acc[m][1][r] * asv[1] + acc[m][2][r] * asv[2];
      float pd = acc[m][0][r] * adv[0] + acc[m][1][r] * adv[1] + acc[m][2][r] * adv[2];
#pragma unroll
      for (int o = 8; o > 0; o >>= 1) { ps += __shfl_xor(ps, o); pd += __shfl_xor(pd, o); }
      if (grow < N_NODES) {
#pragma unroll
        for (int n = 0; n < 3; ++n) {
          int c = n * 16 + cl;
          if (c < NCLS) h2[(size_t)grow * NCLS + c] = acc[m][n][r];
        }
        if (cl == 0) { asrc[grow] = ps; adst[grow] = pd; }
      }
    }
  }
}

// ---------------- agg2: LDS alpha + f32x2 gather (3 edges/iter) + b2 + log_softmax ----------------
__global__ __launch_bounds__(256) void agg2_kernel(const int* __restrict__ offsets,
                                                   const int* __restrict__ edge_src,
                                                   const float* __restrict__ asrc,
                                                   const float* __restrict__ adst,
                                                   const float* __restrict__ h2,
                                                   const float* __restrict__ b2,
                                                   float* __restrict__ out) {
  __shared__ float lalpha[4][MAXD];
  __shared__ int   lsoff[4][MAXD];
  int w = threadIdx.x >> 6;
  int lane = threadIdx.x & 63;
  int n = blockIdx.x * 4 + w;
  int base = offsets[n];
  int deg = offsets[n + 1] - base;
  int degc = min(deg, MAXD);
  int degp = ((degc + 2) / 3) * 3;   // pad to 3

  float advv = adst[n];
  float m = -INFINITY;
  for (int e = lane; e < deg; e += 64) {
    int s = edge_src[base + e];
    float ev = lrelu(asrc[s] + advv);
    if (e < MAXD) { lsoff[w][e] = s * (NCLS * 4); lalpha[w][e] = ev; }
    m = fmaxf(m, ev);
  }
  m = wave_max(m);
  float ssum = 0.f;
  for (int e = lane; e < deg; e += 64) {
    float ev;
    if (e < MAXD) ev = lalpha[w][e];
    else { int s = edge_src[base + e]; ev = lrelu(asrc[s] + advv); }
    ssum += __expf(ev - m);
  }
  float inv = 1.f / (wave_sum(ssum) + 1e-16f);
  for (int e = lane; e < degc; e += 64) lalpha[w][e] = __expf(lalpha[w][e] - m) * inv;
  {
    int e = degc + lane;
    if (e < degp && e < MAXD) { lalpha[w][e] = 0.f; lsoff[w][e] = 0; }
    else if (e < degp) { /* degc==MAXD => degp==MAXD, no pad needed */ }
  }
  // wave-local lalpha/lsoff: no block sync needed

  // heavy loop: 3 edges/iter, 20 lanes per edge, float2 (2 ch) per lane
  int esub = lane / 20;          // 0,1,2 active; esub==3 (lanes 60-63) idle
  int cg = lane - esub * 20;     // 0..19
  bool act = esub < 3;
  float ax = 0.f, ay = 0.f;
  const char* hb = (const char*)h2 + cg * 8;
  for (int i = 0; i < degp; i += 3) {
    if (act) {
      int slot = i + esub;
      float a = lalpha[w][slot];
      int so = lsoff[w][slot];
      float2 hv = *(const float2*)(hb + so);
      ax += a * hv.x; ay += a * hv.y;
    }
  }
  for (int e = MAXD + esub; e < deg; e += 3) {   // guard, never runs
    if (act) {
      int s = edge_src[base + e];
      float a = __expf(lrelu(asrc[s] + advv) - m) * inv;
      float2 hv = *(const float2*)(hb + (size_t)s * (NCLS * 4));
      ax += a * hv.x; ay += a * hv.y;
    }
  }
  // reduce across 3 edge sub-slots: lanes cg, cg+20, cg+40
  float ax1 = __shfl(ax, lane + 20), ax2 = __shfl(ax, lane + 40);
  float ay1 = __shfl(ay, lane + 20), ay2 = __shfl(ay, lane + 40);
  float v0 = -INFINITY, v1 = -INFINITY;
  if (lane < 20) {
    v0 = ax + ax1 + ax2 + b2[2 * cg];
    v1 = ay + ay1 + ay2 + b2[2 * cg + 1];
  }
  float m2 = wave_max(fmaxf(v0, v1));
  float se = wave_sum(lane < 20 ? __expf(v0 - m2) + __expf(v1 - m2) : 0.f);
  if (lane < 20) {
    float ls = logf(se);
    *(float2*)&out[(size_t)n * NCLS + 2 * cg] = make_float2(v0 - m2 - ls, v1 - m2 - ls);
  }
}

extern "C" void kernel_launch(void* const* d_in, const int* in_sizes, int n_in,
                              void* d_out, int out_size, void* d_ws, size_t ws_size,
                              hipStream_t stream) {
  const float* x   = (const float*)d_in[0];
  const int*   ei  = (const int*)d_in[1];
  const float* W1  = (const float*)d_in[2];
  const float* as1 = (const float*)d_in[3];
  const float* ad1 = (const float*)d_in[4];
  const float* b1  = (const float*)d_in[5];
  const float* W2  = (const float*)d_in[6];
  const float* as2 = (const float*)d_in[7];
  const float* ad2 = (const float*)d_in[8];
  const float* b2  = (const float*)d_in[9];
  float* out = (float*)d_out;

  char* ws = (char*)d_ws;
  size_t off = 0;
  auto alloc = [&](size_t bytes) -> char* {
    char* p = ws + off;
    off += (bytes + 255) & ~(size_t)255;
    return p;
  };
  int* deg      = (int*)alloc((size_t)N_NODES * 4);
  int* cursor   = (int*)alloc((size_t)N_NODES * 4);
  int* offsets  = (int*)alloc((size_t)(N_NODES + 1) * 4);
  int* edge_src = (int*)alloc((size_t)EP * 4);
  unsigned short* xb    = (unsigned short*)alloc((size_t)MPAD * F_IN * 2);
  unsigned short* wb1t  = (unsigned short*)alloc((size_t)D1 * F_IN * 2);
  unsigned short* wb2t  = (unsigned short*)alloc((size_t)48 * D1 * 2);
  unsigned short* h1b   = (unsigned short*)alloc((size_t)N_NODES * D1 * 2);
  unsigned short* out1b = (unsigned short*)alloc((size_t)MPAD * D1 * 2);
  float* asrc1  = (float*)alloc((size_t)N_NODES * H1 * 4);
  float* adst1  = (float*)alloc((size_t)N_NODES * H1 * 4);
  float* h2     = (float*)alloc((size_t)N_NODES * NCLS * 4);
  float* asrc2  = (float*)alloc((size_t)N_NODES * 4);
  float* adst2  = (float*)alloc((size_t)N_NODES * 4);

  hipMemsetAsync(deg, 0, (size_t)N_NODES * 4, stream);
  hipMemsetAsync(cursor, 0, (size_t)N_NODES * 4, stream);
  hipMemsetAsync(out1b + (size_t)N_NODES * D1, 0, (size_t)(MPAD - N_NODES) * D1 * 2, stream);

  convert_x<<<(MPAD * F_IN / 8 + 255) / 256, 256, 0, stream>>>(x, xb);
  transpose_w1<<<32, 256, 0, stream>>>(W1, wb1t);
  transpose_w2<<<48, 512, 0, stream>>>(W2, wb2t);

  count_deg<<<(EP + 255) / 256, 256, 0, stream>>>(ei, deg);
  scan_kernel<<<1, SCAN_T, 0, stream>>>(deg, offsets);
  scatter_edges<<<(EP + 255) / 256, 256, 0, stream>>>(ei, offsets, cursor, edge_src);

  gemm1_mfma<<<157 * 4, 256, 0, stream>>>(xb, wb1t, as1, ad1, h1b, asrc1, adst1);
  agg1_kernel<<<N_NODES, 512, 0, stream>>>(offsets, edge_src, asrc1, adst1, h1b, b1, out1b);

  gemm2_mfma<<<157, 256, 0, stream>>>(out1b, wb2t, as2, ad2, h2, asrc2, adst2);
  agg2_kernel<<<N_NODES / 4, 256, 0, stream>>>(offsets, edge_src, asrc2, adst2, h2, b2, out);
}

// Round 5
// 210.669 us; speedup vs baseline: 1.1163x; 1.1163x over previous
//
#include <hip/hip_runtime.h>
#include <hip/hip_bf16.h>
#include <math.h>

#define N_NODES 20000
#define MPAD 20096               // 157*128
#define N_EDGES 320000
#define EP (N_EDGES + N_NODES)   // 340000
#define F_IN 256
#define NHID 64
#define H1 8
#define D1 512
#define NCLS 40
#define NEG_SLOPE 0.2f
#define MAXD 128                 // LDS-cached edges per dst; deg~Poisson(17), P(deg>128)~0

typedef __attribute__((ext_vector_type(8))) short bf16x8;
typedef __attribute__((ext_vector_type(4))) float f32x4;

__device__ __forceinline__ float wave_max(float v) {
#pragma unroll
  for (int o = 32; o > 0; o >>= 1) v = fmaxf(v, __shfl_xor(v, o));
  return v;
}
__device__ __forceinline__ float wave_sum(float v) {
#pragma unroll
  for (int o = 32; o > 0; o >>= 1) v += __shfl_xor(v, o);
  return v;
}
__device__ __forceinline__ float bf2f(unsigned short u) {
  union { unsigned int i; float f; } c; c.i = ((unsigned int)u) << 16; return c.f;
}
__device__ __forceinline__ unsigned short f2bf(float f) {
  union { float f; unsigned int i; } c; c.f = f;
  unsigned int x = c.i;
  return (unsigned short)((x + 0x7fffu + ((x >> 16) & 1u)) >> 16);  // RNE
}
__device__ __forceinline__ float asf(unsigned int u) {
  union { unsigned int i; float f; } c; c.i = u; return c.f;
}
__device__ __forceinline__ float lrelu(float x) { return x > 0.f ? x : NEG_SLOPE * x; }

// async global->LDS, 16B per lane; LDS dest = wave-uniform base + lane*16
__device__ __forceinline__ void gload16(const void* g, void* l) {
  __builtin_amdgcn_global_load_lds((const __attribute__((address_space(1))) void*)g,
                                   (__attribute__((address_space(3))) void*)l, 16, 0, 0);
}

// ---------------- CSR build ----------------
__global__ void count_deg(const int* __restrict__ ei, int* __restrict__ deg) {
  int e = blockIdx.x * blockDim.x + threadIdx.x;
  if (e >= EP) return;
  int dst = (e < N_EDGES) ? ei[N_EDGES + e] : (e - N_EDGES);
  atomicAdd(&deg[dst], 1);
}

#define SCAN_T 256
#define SCAN_CHUNK 79
__global__ void scan_kernel(const int* __restrict__ deg, int* __restrict__ offsets) {
  __shared__ int sums[SCAN_T];
  int t = threadIdx.x;
  int lo = t * SCAN_CHUNK;
  int hi = min(lo + SCAN_CHUNK, N_NODES);
  int s = 0;
  for (int i = lo; i < hi; ++i) s += deg[i];
  sums[t] = s;
  __syncthreads();
  if (t == 0) {
    int run = 0;
    for (int i = 0; i < SCAN_T; ++i) { int v = sums[i]; sums[i] = run; run += v; }
  }
  __syncthreads();
  int run = sums[t];
  for (int i = lo; i < hi; ++i) { offsets[i] = run; run += deg[i]; }
  if (hi == N_NODES) offsets[N_NODES] = run;
}

__global__ void scatter_edges(const int* __restrict__ ei, const int* __restrict__ offsets,
                              int* __restrict__ cursor, int* __restrict__ edge_src) {
  int e = blockIdx.x * blockDim.x + threadIdx.x;
  if (e >= EP) return;
  int src, dst;
  if (e < N_EDGES) { src = ei[e]; dst = ei[N_EDGES + e]; }
  else             { src = dst = e - N_EDGES; }
  int pos = offsets[dst] + atomicAdd(&cursor[dst], 1);
  edge_src[pos] = src;
}

// ---------------- converts ----------------
__global__ void convert_x(const float* __restrict__ x, unsigned short* __restrict__ xb) {
  size_t base = ((size_t)blockIdx.x * blockDim.x + threadIdx.x) * 8;
  int row = (int)(base >> 8);
  ushort4 o0, o1;
  if (row < N_NODES) {
    float4 v0 = *(const float4*)&x[base];
    float4 v1 = *(const float4*)&x[base + 4];
    o0 = make_ushort4(f2bf(v0.x), f2bf(v0.y), f2bf(v0.z), f2bf(v0.w));
    o1 = make_ushort4(f2bf(v1.x), f2bf(v1.y), f2bf(v1.z), f2bf(v1.w));
  } else {
    o0 = make_ushort4(0, 0, 0, 0); o1 = o0;
  }
  *(ushort4*)&xb[base] = o0;
  *(ushort4*)&xb[base + 4] = o1;
}

// W1 [256][512] f32 -> wb1t [512][256] bf16 (transposed)
__global__ __launch_bounds__(256) void transpose_w1(const float* __restrict__ W1,
                                                    unsigned short* __restrict__ wb1t) {
  __shared__ float t[64][65];
  int bk = blockIdx.x & 3, bn = blockIdx.x >> 2;
  int tr = threadIdx.x >> 4, tc4 = (threadIdx.x & 15) * 4;
#pragma unroll
  for (int i = 0; i < 4; ++i) {
    int k = i * 16 + tr;
    float4 v = *(const float4*)&W1[(size_t)(bk * 64 + k) * D1 + bn * 64 + tc4];
    t[k][tc4] = v.x; t[k][tc4 + 1] = v.y; t[k][tc4 + 2] = v.z; t[k][tc4 + 3] = v.w;
  }
  __syncthreads();
#pragma unroll
  for (int i = 0; i < 4; ++i) {
    int n = i * 16 + tr;
    ushort4 o = make_ushort4(f2bf(t[tc4][n]), f2bf(t[tc4 + 1][n]),
                             f2bf(t[tc4 + 2][n]), f2bf(t[tc4 + 3][n]));
    *(ushort4*)&wb1t[(size_t)(bn * 64 + n) * F_IN + bk * 64 + tc4] = o;
  }
}

// W2 [512][40] f32 -> wb2t [48][512] bf16 (transposed, zero-padded cols 40..47)
__global__ void transpose_w2(const float* __restrict__ W2, unsigned short* __restrict__ wb2t) {
  int c = blockIdx.x;   // 0..47
  int k = threadIdx.x;  // 0..511
  float v = (c < NCLS) ? W2[(size_t)k * NCLS + c] : 0.f;
  wb2t[(size_t)c * D1 + k] = f2bf(v);
}

// ---------------- GEMM1 (MFMA): h1b = xb @ W1, fused alpha1 ----------------
__global__ __launch_bounds__(256) void gemm1_mfma(const unsigned short* __restrict__ xb,
                                                  const unsigned short* __restrict__ wb1t,
                                                  const float* __restrict__ a_src,
                                                  const float* __restrict__ a_dst,
                                                  unsigned short* __restrict__ h1b,
                                                  float* __restrict__ asrc,
                                                  float* __restrict__ adst) {
  __shared__ unsigned short As[128 * 32];
  __shared__ unsigned short Bs[128 * 32];
  int tid = threadIdx.x;
  int w = tid >> 6, lane = tid & 63;
  int bn = blockIdx.x & 3, bm = blockIdx.x >> 2;
  int row0 = bm * 128, col0 = bn * 128;
  int wr = w >> 1, wc = w & 1;
  int cl = lane & 15, hi = lane >> 4;
  f32x4 acc[4][4] = {};
  for (int k0 = 0; k0 < F_IN; k0 += 32) {
#pragma unroll
    for (int c = 0; c < 2; ++c) {
      int slot = c * 256 + tid;
      int r = slot >> 2;
      int q = (slot & 3) ^ ((slot >> 3) & 3);   // pre-swizzled source (rule 21)
      gload16(xb + (size_t)(row0 + r) * F_IN + k0 + q * 8, (char*)As + (c * 256 + w * 64) * 16);
      gload16(wb1t + (size_t)(col0 + r) * F_IN + k0 + q * 8, (char*)Bs + (c * 256 + w * 64) * 16);
    }
    __syncthreads();
    bf16x8 a[4], b[4];
#pragma unroll
    for (int m = 0; m < 4; ++m) {
      int r = wr * 64 + m * 16 + cl;
      a[m] = *(const bf16x8*)&As[r * 32 + ((hi ^ ((r >> 1) & 3)) << 3)];
    }
#pragma unroll
    for (int n = 0; n < 4; ++n) {
      int r = wc * 64 + n * 16 + cl;
      b[n] = *(const bf16x8*)&Bs[r * 32 + ((hi ^ ((r >> 1) & 3)) << 3)];
    }
#pragma unroll
    for (int m = 0; m < 4; ++m)
#pragma unroll
      for (int n = 0; n < 4; ++n)
        acc[m][n] = __builtin_amdgcn_mfma_f32_16x16x32_bf16(a[m], b[n], acc[m][n], 0, 0, 0);
    __syncthreads();
  }
  int head = bn * 2 + wc;
  float asv[4], adv[4];
#pragma unroll
  for (int n = 0; n < 4; ++n) {
    asv[n] = a_src[head * 64 + n * 16 + cl];
    adv[n] = a_dst[head * 64 + n * 16 + cl];
  }
#pragma unroll
  for (int m = 0; m < 4; ++m) {
#pragma unroll
    for (int r = 0; r < 4; ++r) {
      int grow = row0 + wr * 64 + m * 16 + hi * 4 + r;
      float ps = acc[m][0][r] * asv[0] + acc[m][1][r] * asv[1] +
                 acc[m][2][r] * asv[2] + acc[m][3][r] * asv[3];
      float pd = acc[m][0][r] * adv[0] + acc[m][1][r] * adv[1] +
                 acc[m][2][r] * adv[2] + acc[m][3][r] * adv[3];
#pragma unroll
      for (int o = 8; o > 0; o >>= 1) { ps += __shfl_xor(ps, o); pd += __shfl_xor(pd, o); }
      if (grow < N_NODES) {
#pragma unroll
        for (int n = 0; n < 4; ++n)
          h1b[(size_t)grow * D1 + col0 + wc * 64 + n * 16 + cl] = f2bf(acc[m][n][r]);
        if (cl == 0) { asrc[grow * H1 + head] = ps; adst[grow * H1 + head] = pd; }
      }
    }
  }
}

// ---------------- agg1: softmax (per-head waves) then full-row-per-edge gather ----------------
// Gather phase: wave w handles edges w, w+8, ... Each edge's entire 1KB row is read by
// the 64 lanes (16B/lane = 8 channels); lane's head = lane>>3. Zero padding waste.
__global__ __launch_bounds__(512) void agg1_kernel(const int* __restrict__ offsets,
                                                   const int* __restrict__ edge_src,
                                                   const float* __restrict__ asrc,
                                                   const float* __restrict__ adst,
                                                   const unsigned short* __restrict__ h1b,
                                                   const float* __restrict__ b1,
                                                   unsigned short* __restrict__ out1b) {
  __shared__ float alphaT[MAXD][H1 + 1];   // stride 9: bank-spread for per-head access
  __shared__ int   lsoff[MAXD];
  __shared__ float minv[H1][2];
  __shared__ float accs[H1][D1];           // 16KB partial sums
  int n = blockIdx.x;
  int w = threadIdx.x >> 6;
  int lane = threadIdx.x & 63;
  int base = offsets[n];
  int deg = offsets[n + 1] - base;
  int degc = min(deg, MAXD);

  for (int e = (int)threadIdx.x; e < degc; e += 512) lsoff[e] = edge_src[base + e] << 10;
  __syncthreads();

  // softmax phase: wave w == head h
  {
    int h = w;
    float advv = adst[n * H1 + h];
    float m = -INFINITY;
    for (int e = lane; e < deg; e += 64) {
      int s = (e < MAXD) ? (lsoff[e] >> 10) : edge_src[base + e];
      float ev = lrelu(asrc[s * H1 + h] + advv);
      if (e < MAXD) alphaT[e][h] = ev;
      m = fmaxf(m, ev);
    }
    m = wave_max(m);
    float ssum = 0.f;
    for (int e = lane; e < deg; e += 64) {
      float ev;
      if (e < MAXD) ev = alphaT[e][h];
      else ev = lrelu(asrc[edge_src[base + e] * H1 + h] + advv);
      ssum += __expf(ev - m);
    }
    float inv = 1.f / (wave_sum(ssum) + 1e-16f);
    for (int e = lane; e < degc; e += 64) alphaT[e][h] = __expf(alphaT[e][h] - m) * inv;
    if (lane == 0) { minv[h][0] = m; minv[h][1] = inv; }
  }
  __syncthreads();

  // gather phase
  int myh = lane >> 3;
  const char* hb = (const char*)h1b + lane * 16;
  float acc[8] = {};
  for (int e = w; e < degc; e += 8) {
    float a = alphaT[e][myh];
    uint4 uv = *(const uint4*)(hb + lsoff[e]);
#pragma unroll
    for (int j = 0; j < 4; ++j) {
      unsigned int u = ((const unsigned int*)&uv)[j];
      acc[2 * j]     += a * asf(u << 16);
      acc[2 * j + 1] += a * asf(u & 0xffff0000u);
    }
  }
  if (deg > MAXD) {   // correctness guard; never runs for this graph
    float mh = minv[myh][0], invh = minv[myh][1];
    float advh = adst[n * H1 + myh];
    for (int e = MAXD + w; e < deg; e += 8) {
      int s = edge_src[base + e];
      float a = __expf(lrelu(asrc[s * H1 + myh] + advh) - mh) * invh;
      uint4 uv = *(const uint4*)(hb + ((size_t)s << 10));
#pragma unroll
      for (int j = 0; j < 4; ++j) {
        unsigned int u = ((const unsigned int*)&uv)[j];
        acc[2 * j]     += a * asf(u << 16);
        acc[2 * j + 1] += a * asf(u & 0xffff0000u);
      }
    }
  }
  *(float4*)&accs[w][lane * 8]     = make_float4(acc[0], acc[1], acc[2], acc[3]);
  *(float4*)&accs[w][lane * 8 + 4] = make_float4(acc[4], acc[5], acc[6], acc[7]);
  __syncthreads();

  // block reduce: thread t owns channel t (contiguous, conflict-free LDS reads)
  int t = threadIdx.x;
  float s = 0.f;
#pragma unroll
  for (int w2 = 0; w2 < H1; ++w2) s += accs[w2][t];
  float v = s + b1[t];
  v = v > 0.f ? v : (__expf(v) - 1.f);   // ELU
  out1b[(size_t)n * D1 + t] = f2bf(v);
}

// ---------------- GEMM2 (MFMA): h2 = out1b @ W2 (+pad), fused alpha2 ----------------
__global__ __launch_bounds__(256) void gemm2_mfma(const unsigned short* __restrict__ ab,
                                                  const unsigned short* __restrict__ wb2t,
                                                  const float* __restrict__ a_src2,
                                                  const float* __restrict__ a_dst2,
                                                  float* __restrict__ h2,
                                                  float* __restrict__ asrc,
                                                  float* __restrict__ adst) {
  __shared__ unsigned short As[128 * 32];
  __shared__ unsigned short Bs[48 * 32];
  int tid = threadIdx.x;
  int w = tid >> 6, lane = tid & 63;
  int row0 = blockIdx.x * 128;
  int cl = lane & 15, hi = lane >> 4;
  f32x4 acc[2][3] = {};
  for (int k0 = 0; k0 < D1; k0 += 32) {
#pragma unroll
    for (int c = 0; c < 2; ++c) {
      int slot = c * 256 + tid;
      int r = slot >> 2;
      int q = (slot & 3) ^ ((slot >> 3) & 3);
      gload16(ab + (size_t)(row0 + r) * D1 + k0 + q * 8, (char*)As + (c * 256 + w * 64) * 16);
    }
    if (tid < 192) {
      int r = tid >> 2;
      int q = (tid & 3) ^ ((tid >> 3) & 3);
      gload16(wb2t + (size_t)r * D1 + k0 + q * 8, (char*)Bs + w * 64 * 16);
    }
    __syncthreads();
    bf16x8 a[2], b[3];
#pragma unroll
    for (int m = 0; m < 2; ++m) {
      int r = w * 32 + m * 16 + cl;
      a[m] = *(const bf16x8*)&As[r * 32 + ((hi ^ ((r >> 1) & 3)) << 3)];
    }
#pragma unroll
    for (int n = 0; n < 3; ++n) {
      int r = n * 16 + cl;
      b[n] = *(const bf16x8*)&Bs[r * 32 + ((hi ^ ((r >> 1) & 3)) << 3)];
    }
#pragma unroll
    for (int m = 0; m < 2; ++m)
#pragma unroll
      for (int n = 0; n < 3; ++n)
        acc[m][n] = __builtin_amdgcn_mfma_f32_16x16x32_bf16(a[m], b[n], acc[m][n], 0, 0, 0);
    __syncthreads();
  }
  float asv[3], adv[3];
#pragma unroll
  for (int n = 0; n < 3; ++n) {
    int c = n * 16 + cl;
    asv[n] = (c < NCLS) ? a_src2[c] : 0.f;
    adv[n] = (c < NCLS) ? a_dst2[c] : 0.f;
  }
#pragma unroll
  for (int m = 0; m < 2; ++m) {
#pragma unroll
    for (int r = 0; r < 4; ++r) {
      int grow = row0 + w * 32 + m * 16 + hi * 4 + r;
      float ps = acc[m][0][r] * asv[0] + acc[m][1][r] * asv[1] + acc[m][2][r] * asv[2];
      float pd = acc[m][0][r] * adv[0] + acc[m][1][r] * adv[1] + acc[m][2][r] * adv[2];
#pragma unroll
      for (int o = 8; o > 0; o >>= 1) { ps += __shfl_xor(ps, o); pd += __shfl_xor(pd, o); }
      if (grow < N_NODES) {
#pragma unroll
        for (int n = 0; n < 3; ++n) {
          int c = n * 16 + cl;
          if (c < NCLS) h2[(size_t)grow * NCLS + c] = acc[m][n][r];
        }
        if (cl == 0) { asrc[grow] = ps; adst[grow] = pd; }
      }
    }
  }
}

// ---------------- agg2: LDS alpha + f32x2 gather (3 edges/iter) + b2 + log_softmax ----------------
__global__ __launch_bounds__(256) void agg2_kernel(const int* __restrict__ offsets,
                                                   const int* __restrict__ edge_src,
                                                   const float* __restrict__ asrc,
                                                   const float* __restrict__ adst,
                                                   const float* __restrict__ h2,
                                                   const float* __restrict__ b2,
                                                   float* __restrict__ out) {
  __shared__ float lalpha[4][MAXD];
  __shared__ int   lsoff[4][MAXD];
  int w = threadIdx.x >> 6;
  int lane = threadIdx.x & 63;
  int n = blockIdx.x * 4 + w;
  int base = offsets[n];
  int deg = offsets[n + 1] - base;
  int degc = min(deg, MAXD);
  int degp = ((degc + 2) / 3) * 3;   // pad to 3

  float advv = adst[n];
  float m = -INFINITY;
  for (int e = lane; e < deg; e += 64) {
    int s = edge_src[base + e];
    float ev = lrelu(asrc[s] + advv);
    if (e < MAXD) { lsoff[w][e] = s * (NCLS * 4); lalpha[w][e] = ev; }
    m = fmaxf(m, ev);
  }
  m = wave_max(m);
  float ssum = 0.f;
  for (int e = lane; e < deg; e += 64) {
    float ev;
    if (e < MAXD) ev = lalpha[w][e];
    else { int s = edge_src[base + e]; ev = lrelu(asrc[s] + advv); }
    ssum += __expf(ev - m);
  }
  float inv = 1.f / (wave_sum(ssum) + 1e-16f);
  for (int e = lane; e < degc; e += 64) lalpha[w][e] = __expf(lalpha[w][e] - m) * inv;
  {
    int e = degc + lane;
    if (e < degp && e < MAXD) { lalpha[w][e] = 0.f; lsoff[w][e] = 0; }
  }
  // wave-local lalpha/lsoff: no block sync needed

  int esub = lane / 20;          // 0,1,2 active; lanes 60-63 idle
  int cg = lane - esub * 20;     // 0..19
  bool act = esub < 3;
  float ax = 0.f, ay = 0.f;
  const char* hb = (const char*)h2 + cg * 8;
  for (int i = 0; i < degp; i += 3) {
    if (act) {
      int slot = i + esub;
      float a = lalpha[w][slot];
      int so = lsoff[w][slot];
      float2 hv = *(const float2*)(hb + so);
      ax += a * hv.x; ay += a * hv.y;
    }
  }
  for (int e = MAXD + esub; e < deg; e += 3) {   // guard, never runs
    if (act) {
      int s = edge_src[base + e];
      float a = __expf(lrelu(asrc[s] + advv) - m) * inv;
      float2 hv = *(const float2*)(hb + (size_t)s * (NCLS * 4));
      ax += a * hv.x; ay += a * hv.y;
    }
  }
  float ax1 = __shfl(ax, lane + 20), ax2 = __shfl(ax, lane + 40);
  float ay1 = __shfl(ay, lane + 20), ay2 = __shfl(ay, lane + 40);
  float v0 = -INFINITY, v1 = -INFINITY;
  if (lane < 20) {
    v0 = ax + ax1 + ax2 + b2[2 * cg];
    v1 = ay + ay1 + ay2 + b2[2 * cg + 1];
  }
  float m2 = wave_max(fmaxf(v0, v1));
  float se = wave_sum(lane < 20 ? __expf(v0 - m2) + __expf(v1 - m2) : 0.f);
  if (lane < 20) {
    float ls = logf(se);
    *(float2*)&out[(size_t)n * NCLS + 2 * cg] = make_float2(v0 - m2 - ls, v1 - m2 - ls);
  }
}

extern "C" void kernel_launch(void* const* d_in, const int* in_sizes, int n_in,
                              void* d_out, int out_size, void* d_ws, size_t ws_size,
                              hipStream_t stream) {
  const float* x   = (const float*)d_in[0];
  const int*   ei  = (const int*)d_in[1];
  const float* W1  = (const float*)d_in[2];
  const float* as1 = (const float*)d_in[3];
  const float* ad1 = (const float*)d_in[4];
  const float* b1  = (const float*)d_in[5];
  const float* W2  = (const float*)d_in[6];
  const float* as2 = (const float*)d_in[7];
  const float* ad2 = (const float*)d_in[8];
  const float* b2  = (const float*)d_in[9];
  float* out = (float*)d_out;

  char* ws = (char*)d_ws;
  size_t off = 0;
  auto alloc = [&](size_t bytes) -> char* {
    char* p = ws + off;
    off += (bytes + 255) & ~(size_t)255;
    return p;
  };
  int* deg      = (int*)alloc((size_t)N_NODES * 4);
  int* cursor   = (int*)alloc((size_t)N_NODES * 4);
  int* offsets  = (int*)alloc((size_t)(N_NODES + 1) * 4);
  int* edge_src = (int*)alloc((size_t)EP * 4);
  unsigned short* xb    = (unsigned short*)alloc((size_t)MPAD * F_IN * 2);
  unsigned short* wb1t  = (unsigned short*)alloc((size_t)D1 * F_IN * 2);
  unsigned short* wb2t  = (unsigned short*)alloc((size_t)48 * D1 * 2);
  unsigned short* h1b   = (unsigned short*)alloc((size_t)N_NODES * D1 * 2);
  unsigned short* out1b = (unsigned short*)alloc((size_t)MPAD * D1 * 2);
  float* asrc1  = (float*)alloc((size_t)N_NODES * H1 * 4);
  float* adst1  = (float*)alloc((size_t)N_NODES * H1 * 4);
  float* h2     = (float*)alloc((size_t)N_NODES * NCLS * 4);
  float* asrc2  = (float*)alloc((size_t)N_NODES * 4);
  float* adst2  = (float*)alloc((size_t)N_NODES * 4);

  hipMemsetAsync(deg, 0, (size_t)N_NODES * 4, stream);
  hipMemsetAsync(cursor, 0, (size_t)N_NODES * 4, stream);
  hipMemsetAsync(out1b + (size_t)N_NODES * D1, 0, (size_t)(MPAD - N_NODES) * D1 * 2, stream);

  convert_x<<<(MPAD * F_IN / 8 + 255) / 256, 256, 0, stream>>>(x, xb);
  transpose_w1<<<32, 256, 0, stream>>>(W1, wb1t);
  transpose_w2<<<48, 512, 0, stream>>>(W2, wb2t);

  count_deg<<<(EP + 255) / 256, 256, 0, stream>>>(ei, deg);
  scan_kernel<<<1, SCAN_T, 0, stream>>>(deg, offsets);
  scatter_edges<<<(EP + 255) / 256, 256, 0, stream>>>(ei, offsets, cursor, edge_src);

  gemm1_mfma<<<157 * 4, 256, 0, stream>>>(xb, wb1t, as1, ad1, h1b, asrc1, adst1);
  agg1_kernel<<<N_NODES, 512, 0, stream>>>(offsets, edge_src, asrc1, adst1, h1b, b1, out1b);

  gemm2_mfma<<<157, 256, 0, stream>>>(out1b, wb2t, as2, ad2, h2, asrc2, adst2);
  agg2_kernel<<<N_NODES / 4, 256, 0, stream>>>(offsets, edge_src, asrc2, adst2, h2, b2, out);
}

// Round 6
// 172.570 us; speedup vs baseline: 1.3627x; 1.2208x over previous
//
#include <hip/hip_runtime.h>
#include <hip/hip_bf16.h>
#include <math.h>

#define N_NODES 20000
#define MPAD 20096               // 157*128
#define N_EDGES 320000
#define EP (N_EDGES + N_NODES)   // 340000
#define F_IN 256
#define NHID 64
#define H1 8
#define D1 512
#define NCLS 40
#define NEG_SLOPE 0.2f
#define MAXD 128                 // LDS-cached edges per dst; deg~Poisson(17)

typedef __attribute__((ext_vector_type(8))) short bf16x8;
typedef __attribute__((ext_vector_type(4))) float f32x4;

__device__ __forceinline__ float wave_max(float v) {
#pragma unroll
  for (int o = 32; o > 0; o >>= 1) v = fmaxf(v, __shfl_xor(v, o));
  return v;
}
__device__ __forceinline__ float wave_sum(float v) {
#pragma unroll
  for (int o = 32; o > 0; o >>= 1) v += __shfl_xor(v, o);
  return v;
}
__device__ __forceinline__ float bf2f(unsigned short u) {
  union { unsigned int i; float f; } c; c.i = ((unsigned int)u) << 16; return c.f;
}
__device__ __forceinline__ unsigned short f2bf(float f) {
  union { float f; unsigned int i; } c; c.f = f;
  unsigned int x = c.i;
  return (unsigned short)((x + 0x7fffu + ((x >> 16) & 1u)) >> 16);  // RNE
}
__device__ __forceinline__ float asf(unsigned int u) {
  union { unsigned int i; float f; } c; c.i = u; return c.f;
}
__device__ __forceinline__ float lrelu(float x) { return x > 0.f ? x : NEG_SLOPE * x; }

__device__ __forceinline__ void gload16(const void* g, void* l) {
  __builtin_amdgcn_global_load_lds((const __attribute__((address_space(1))) void*)g,
                                   (__attribute__((address_space(3))) void*)l, 16, 0, 0);
}

// ---------------- fused prep: convert_x | transpose_w1 | transpose_w2 | zero deg/cursor | zero pad ----------------
#define PB_CONV 2512             // MPAD*F_IN/8/256
#define PB_TW1  (PB_CONV + 32)
#define PB_TW2  (PB_TW1 + 96)    // 48*512/256
#define PB_ZERO (PB_TW2 + 157)   // 40000 ints
#define PB_PAD  (PB_ZERO + 24)   // 96*512 bf16 = 98304B = 6144*16B
__global__ __launch_bounds__(256) void prep_kernel(const float* __restrict__ x,
                                                   const float* __restrict__ W1,
                                                   const float* __restrict__ W2,
                                                   unsigned short* __restrict__ xb,
                                                   unsigned short* __restrict__ wb1t,
                                                   unsigned short* __restrict__ wb2t,
                                                   int* __restrict__ deg,
                                                   int* __restrict__ cursor,
                                                   unsigned short* __restrict__ out1b) {
  __shared__ float tsh[64][65];
  int bid = blockIdx.x;
  int t = threadIdx.x;
  if (bid < PB_CONV) {
    size_t base = ((size_t)bid * 256 + t) * 8;
    int row = (int)(base >> 8);
    ushort4 o0, o1;
    if (row < N_NODES) {
      float4 v0 = *(const float4*)&x[base];
      float4 v1 = *(const float4*)&x[base + 4];
      o0 = make_ushort4(f2bf(v0.x), f2bf(v0.y), f2bf(v0.z), f2bf(v0.w));
      o1 = make_ushort4(f2bf(v1.x), f2bf(v1.y), f2bf(v1.z), f2bf(v1.w));
    } else {
      o0 = make_ushort4(0, 0, 0, 0); o1 = o0;
    }
    *(ushort4*)&xb[base] = o0;
    *(ushort4*)&xb[base + 4] = o1;
  } else if (bid < PB_TW1) {
    int b2 = bid - PB_CONV;
    int bk = b2 & 3, bn = b2 >> 2;
    int tr = t >> 4, tc4 = (t & 15) * 4;
#pragma unroll
    for (int i = 0; i < 4; ++i) {
      int k = i * 16 + tr;
      float4 v = *(const float4*)&W1[(size_t)(bk * 64 + k) * D1 + bn * 64 + tc4];
      tsh[k][tc4] = v.x; tsh[k][tc4 + 1] = v.y; tsh[k][tc4 + 2] = v.z; tsh[k][tc4 + 3] = v.w;
    }
    __syncthreads();
#pragma unroll
    for (int i = 0; i < 4; ++i) {
      int n = i * 16 + tr;
      ushort4 o = make_ushort4(f2bf(tsh[tc4][n]), f2bf(tsh[tc4 + 1][n]),
                               f2bf(tsh[tc4 + 2][n]), f2bf(tsh[tc4 + 3][n]));
      *(ushort4*)&wb1t[(size_t)(bn * 64 + n) * F_IN + bk * 64 + tc4] = o;
    }
  } else if (bid < PB_TW2) {
    int idx = (bid - PB_TW1) * 256 + t;   // 0..24575 = c*512 + k
    int c = idx >> 9, k = idx & 511;
    wb2t[idx] = f2bf((c < NCLS) ? W2[(size_t)k * NCLS + c] : 0.f);
  } else if (bid < PB_ZERO) {
    int idx = (bid - PB_TW2) * 256 + t;
    if (idx < N_NODES) deg[idx] = 0;
    else if (idx < 2 * N_NODES) cursor[idx - N_NODES] = 0;
  } else {
    int idx = (bid - PB_ZERO) * 256 + t;  // 0..6143, 16B each
    uint4 z = make_uint4(0, 0, 0, 0);
    *(uint4*)((char*)out1b + (size_t)N_NODES * D1 * 2 + (size_t)idx * 16) = z;
  }
}

// ---------------- CSR build ----------------
__global__ void count_deg(const int* __restrict__ ei, int* __restrict__ deg) {
  int e = blockIdx.x * blockDim.x + threadIdx.x;
  if (e >= EP) return;
  int dst = (e < N_EDGES) ? ei[N_EDGES + e] : (e - N_EDGES);
  atomicAdd(&deg[dst], 1);
}

#define SCAN_T 256
#define SCAN_CHUNK 79
__global__ void scan_kernel(const int* __restrict__ deg, int* __restrict__ offsets) {
  __shared__ int sums[SCAN_T];
  int t = threadIdx.x;
  int lo = t * SCAN_CHUNK;
  int hi = min(lo + SCAN_CHUNK, N_NODES);
  int s = 0;
  for (int i = lo; i < hi; ++i) s += deg[i];
  sums[t] = s;
  __syncthreads();
  if (t == 0) {
    int run = 0;
    for (int i = 0; i < SCAN_T; ++i) { int v = sums[i]; sums[i] = run; run += v; }
  }
  __syncthreads();
  int run = sums[t];
  for (int i = lo; i < hi; ++i) { offsets[i] = run; run += deg[i]; }
  if (hi == N_NODES) offsets[N_NODES] = run;
}

__global__ void scatter_edges(const int* __restrict__ ei, const int* __restrict__ offsets,
                              int* __restrict__ cursor, int* __restrict__ edge_src) {
  int e = blockIdx.x * blockDim.x + threadIdx.x;
  if (e >= EP) return;
  int src, dst;
  if (e < N_EDGES) { src = ei[e]; dst = ei[N_EDGES + e]; }
  else             { src = dst = e - N_EDGES; }
  int pos = offsets[dst] + atomicAdd(&cursor[dst], 1);
  edge_src[pos] = src;
}

// ---------------- GEMM1 (MFMA): h1b = xb @ W1, fused alpha1 ----------------
__global__ __launch_bounds__(256) void gemm1_mfma(const unsigned short* __restrict__ xb,
                                                  const unsigned short* __restrict__ wb1t,
                                                  const float* __restrict__ a_src,
                                                  const float* __restrict__ a_dst,
                                                  unsigned short* __restrict__ h1b,
                                                  float* __restrict__ asrc,
                                                  float* __restrict__ adst) {
  __shared__ unsigned short As[128 * 32];
  __shared__ unsigned short Bs[128 * 32];
  int tid = threadIdx.x;
  int w = tid >> 6, lane = tid & 63;
  int bn = blockIdx.x & 3, bm = blockIdx.x >> 2;
  int row0 = bm * 128, col0 = bn * 128;
  int wr = w >> 1, wc = w & 1;
  int cl = lane & 15, hi = lane >> 4;
  f32x4 acc[4][4] = {};
  for (int k0 = 0; k0 < F_IN; k0 += 32) {
#pragma unroll
    for (int c = 0; c < 2; ++c) {
      int slot = c * 256 + tid;
      int r = slot >> 2;
      int q = (slot & 3) ^ ((slot >> 3) & 3);   // pre-swizzled source (rule 21)
      gload16(xb + (size_t)(row0 + r) * F_IN + k0 + q * 8, (char*)As + (c * 256 + w * 64) * 16);
      gload16(wb1t + (size_t)(col0 + r) * F_IN + k0 + q * 8, (char*)Bs + (c * 256 + w * 64) * 16);
    }
    __syncthreads();
    bf16x8 a[4], b[4];
#pragma unroll
    for (int m = 0; m < 4; ++m) {
      int r = wr * 64 + m * 16 + cl;
      a[m] = *(const bf16x8*)&As[r * 32 + ((hi ^ ((r >> 1) & 3)) << 3)];
    }
#pragma unroll
    for (int n = 0; n < 4; ++n) {
      int r = wc * 64 + n * 16 + cl;
      b[n] = *(const bf16x8*)&Bs[r * 32 + ((hi ^ ((r >> 1) & 3)) << 3)];
    }
#pragma unroll
    for (int m = 0; m < 4; ++m)
#pragma unroll
      for (int n = 0; n < 4; ++n)
        acc[m][n] = __builtin_amdgcn_mfma_f32_16x16x32_bf16(a[m], b[n], acc[m][n], 0, 0, 0);
    __syncthreads();
  }
  int head = bn * 2 + wc;
  float asv[4], adv[4];
#pragma unroll
  for (int n = 0; n < 4; ++n) {
    asv[n] = a_src[head * 64 + n * 16 + cl];
    adv[n] = a_dst[head * 64 + n * 16 + cl];
  }
#pragma unroll
  for (int m = 0; m < 4; ++m) {
#pragma unroll
    for (int r = 0; r < 4; ++r) {
      int grow = row0 + wr * 64 + m * 16 + hi * 4 + r;
      float ps = acc[m][0][r] * asv[0] + acc[m][1][r] * asv[1] +
                 acc[m][2][r] * asv[2] + acc[m][3][r] * asv[3];
      float pd = acc[m][0][r] * adv[0] + acc[m][1][r] * adv[1] +
                 acc[m][2][r] * adv[2] + acc[m][3][r] * adv[3];
#pragma unroll
      for (int o = 8; o > 0; o >>= 1) { ps += __shfl_xor(ps, o); pd += __shfl_xor(pd, o); }
      if (grow < N_NODES) {
#pragma unroll
        for (int n = 0; n < 4; ++n)
          h1b[(size_t)grow * D1 + col0 + wc * 64 + n * 16 + cl] = f2bf(acc[m][n][r]);
        if (cl == 0) { asrc[grow * H1 + head] = ps; adst[grow * H1 + head] = pd; }
      }
    }
  }
}

// ---------------- agg1: 128-thr/node; (edge,head)-parallel softmax + full-row gather ----------------
__global__ __launch_bounds__(128) void agg1_kernel(const int* __restrict__ offsets,
                                                   const int* __restrict__ edge_src,
                                                   const float* __restrict__ asrc,
                                                   const float* __restrict__ adst,
                                                   const unsigned short* __restrict__ h1b,
                                                   const float* __restrict__ b1,
                                                   unsigned short* __restrict__ out1b) {
  __shared__ float alphaT[MAXD][H1 + 1];
  __shared__ int   lsoff[MAXD];
  __shared__ float red[2][8];
  __shared__ float minv[2][8];
  __shared__ float accs[2][D1];
  int n = blockIdx.x;
  int t = threadIdx.x;
  int w = t >> 6, lane = t & 63;
  int base = offsets[n];
  int deg = offsets[n + 1] - base;
  int degc = min(deg, MAXD);

  for (int e = t; e < degc; e += 128) lsoff[e] = edge_src[base + e] << 10;
  __syncthreads();

  // softmax: thread = (edge et, head h); 16 edges x 8 heads per iteration
  int h = t & 7;
  int et = t >> 3;
  float advv = adst[n * H1 + h];
  float m = -INFINITY;
  for (int e = et; e < degc; e += 16) {
    int s = lsoff[e] >> 10;
    float ev = lrelu(asrc[s * H1 + h] + advv);
    alphaT[e][h] = ev;
    m = fmaxf(m, ev);
  }
  for (int e = MAXD + et; e < deg; e += 16)   // guard, never runs for this graph
    m = fmaxf(m, lrelu(asrc[edge_src[base + e] * H1 + h] + advv));
  m = fmaxf(m, __shfl_xor(m, 8));
  m = fmaxf(m, __shfl_xor(m, 16));
  m = fmaxf(m, __shfl_xor(m, 32));
  if (lane < 8) red[w][lane] = m;
  __syncthreads();
  m = fmaxf(red[0][h], red[1][h]);
  float ss = 0.f;
  for (int e = et; e < degc; e += 16) ss += __expf(alphaT[e][h] - m);
  for (int e = MAXD + et; e < deg; e += 16)
    ss += __expf(lrelu(asrc[edge_src[base + e] * H1 + h] + advv) - m);
  ss += __shfl_xor(ss, 8);
  ss += __shfl_xor(ss, 16);
  ss += __shfl_xor(ss, 32);
  __syncthreads();              // everyone done reading red (max)
  if (lane < 8) red[w][lane] = ss;
  __syncthreads();
  float inv = 1.f / (red[0][h] + red[1][h] + 1e-16f);
  if (t < 8) { minv[0][t] = m; minv[1][t] = inv; }   // h==t for t<8
  for (int e = et; e < degc; e += 16)
    alphaT[e][h] = __expf(alphaT[e][h] - m) * inv;
  __syncthreads();

  // gather: wave w handles edges w, w+2, ...; 64 lanes x 16B cover the full 1KB row
  int myh = lane >> 3;
  const char* hb = (const char*)h1b + lane * 16;
  float acc[8] = {};
  for (int e = w; e < degc; e += 2) {
    float a = alphaT[e][myh];
    uint4 uv = *(const uint4*)(hb + lsoff[e]);
#pragma unroll
    for (int j = 0; j < 4; ++j) {
      unsigned int u = ((const unsigned int*)&uv)[j];
      acc[2 * j]     += a * asf(u << 16);
      acc[2 * j + 1] += a * asf(u & 0xffff0000u);
    }
  }
  if (deg > MAXD) {             // guard, never runs for this graph
    float mh = minv[0][myh], invh = minv[1][myh];
    float advh = adst[n * H1 + myh];
    for (int e = MAXD + w; e < deg; e += 2) {
      int s = edge_src[base + e];
      float a = __expf(lrelu(asrc[s * H1 + myh] + advh) - mh) * invh;
      uint4 uv = *(const uint4*)(hb + ((size_t)s << 10));
#pragma unroll
      for (int j = 0; j < 4; ++j) {
        unsigned int u = ((const unsigned int*)&uv)[j];
        acc[2 * j]     += a * asf(u << 16);
        acc[2 * j + 1] += a * asf(u & 0xffff0000u);
      }
    }
  }
  *(float4*)&accs[w][lane * 8]     = make_float4(acc[0], acc[1], acc[2], acc[3]);
  *(float4*)&accs[w][lane * 8 + 4] = make_float4(acc[4], acc[5], acc[6], acc[7]);
  __syncthreads();

  // reduce: thread t owns channels [4t, 4t+4)
  int c0 = t * 4;
  float4 s0 = *(float4*)&accs[0][c0];
  float4 s1 = *(float4*)&accs[1][c0];
  float4 bv = *(const float4*)&b1[c0];
  float v0 = s0.x + s1.x + bv.x, v1 = s0.y + s1.y + bv.y;
  float v2 = s0.z + s1.z + bv.z, v3 = s0.w + s1.w + bv.w;
  v0 = v0 > 0.f ? v0 : (__expf(v0) - 1.f);
  v1 = v1 > 0.f ? v1 : (__expf(v1) - 1.f);
  v2 = v2 > 0.f ? v2 : (__expf(v2) - 1.f);
  v3 = v3 > 0.f ? v3 : (__expf(v3) - 1.f);
  ushort4 o = make_ushort4(f2bf(v0), f2bf(v1), f2bf(v2), f2bf(v3));
  *(ushort4*)&out1b[(size_t)n * D1 + c0] = o;
}

// ---------------- GEMM2 (MFMA): h2 = out1b @ W2 (+pad), fused alpha2 ----------------
__global__ __launch_bounds__(256) void gemm2_mfma(const unsigned short* __restrict__ ab,
                                                  const unsigned short* __restrict__ wb2t,
                                                  const float* __restrict__ a_src2,
                                                  const float* __restrict__ a_dst2,
                                                  float* __restrict__ h2,
                                                  float* __restrict__ asrc,
                                                  float* __restrict__ adst) {
  __shared__ unsigned short As[128 * 32];
  __shared__ unsigned short Bs[48 * 32];
  int tid = threadIdx.x;
  int w = tid >> 6, lane = tid & 63;
  int row0 = blockIdx.x * 128;
  int cl = lane & 15, hi = lane >> 4;
  f32x4 acc[2][3] = {};
  for (int k0 = 0; k0 < D1; k0 += 32) {
#pragma unroll
    for (int c = 0; c < 2; ++c) {
      int slot = c * 256 + tid;
      int r = slot >> 2;
      int q = (slot & 3) ^ ((slot >> 3) & 3);
      gload16(ab + (size_t)(row0 + r) * D1 + k0 + q * 8, (char*)As + (c * 256 + w * 64) * 16);
    }
    if (tid < 192) {
      int r = tid >> 2;
      int q = (tid & 3) ^ ((tid >> 3) & 3);
      gload16(wb2t + (size_t)r * D1 + k0 + q * 8, (char*)Bs + w * 64 * 16);
    }
    __syncthreads();
    bf16x8 a[2], b[3];
#pragma unroll
    for (int m = 0; m < 2; ++m) {
      int r = w * 32 + m * 16 + cl;
      a[m] = *(const bf16x8*)&As[r * 32 + ((hi ^ ((r >> 1) & 3)) << 3)];
    }
#pragma unroll
    for (int n = 0; n < 3; ++n) {
      int r = n * 16 + cl;
      b[n] = *(const bf16x8*)&Bs[r * 32 + ((hi ^ ((r >> 1) & 3)) << 3)];
    }
#pragma unroll
    for (int m = 0; m < 2; ++m)
#pragma unroll
      for (int n = 0; n < 3; ++n)
        acc[m][n] = __builtin_amdgcn_mfma_f32_16x16x32_bf16(a[m], b[n], acc[m][n], 0, 0, 0);
    __syncthreads();
  }
  float asv[3], adv[3];
#pragma unroll
  for (int n = 0; n < 3; ++n) {
    int c = n * 16 + cl;
    asv[n] = (c < NCLS) ? a_src2[c] : 0.f;
    adv[n] = (c < NCLS) ? a_dst2[c] : 0.f;
  }
#pragma unroll
  for (int m = 0; m < 2; ++m) {
#pragma unroll
    for (int r = 0; r < 4; ++r) {
      int grow = row0 + w * 32 + m * 16 + hi * 4 + r;
      float ps = acc[m][0][r] * asv[0] + acc[m][1][r] * asv[1] + acc[m][2][r] * asv[2];
      float pd = acc[m][0][r] * adv[0] + acc[m][1][r] * adv[1] + acc[m][2][r] * adv[2];
#pragma unroll
      for (int o = 8; o > 0; o >>= 1) { ps += __shfl_xor(ps, o); pd += __shfl_xor(pd, o); }
      if (grow < N_NODES) {
#pragma unroll
        for (int n = 0; n < 3; ++n) {
          int c = n * 16 + cl;
          if (c < NCLS) h2[(size_t)grow * NCLS + c] = acc[m][n][r];
        }
        if (cl == 0) { asrc[grow] = ps; adst[grow] = pd; }
      }
    }
  }
}

// ---------------- agg2: LDS alpha + f32x2 gather (3 edges/iter) + b2 + log_softmax ----------------
__global__ __launch_bounds__(256) void agg2_kernel(const int* __restrict__ offsets,
                                                   const int* __restrict__ edge_src,
                                                   const float* __restrict__ asrc,
                                                   const float* __restrict__ adst,
                                                   const float* __restrict__ h2,
                                                   const float* __restrict__ b2,
                                                   float* __restrict__ out) {
  __shared__ float lalpha[4][MAXD];
  __shared__ int   lsoff[4][MAXD];
  int w = threadIdx.x >> 6;
  int lane = threadIdx.x & 63;
  int n = blockIdx.x * 4 + w;
  int base = offsets[n];
  int deg = offsets[n + 1] - base;
  int degc = min(deg, MAXD);
  int degp = ((degc + 2) / 3) * 3;

  float advv = adst[n];
  float m = -INFINITY;
  for (int e = lane; e < deg; e += 64) {
    int s = edge_src[base + e];
    float ev = lrelu(asrc[s] + advv);
    if (e < MAXD) { lsoff[w][e] = s * (NCLS * 4); lalpha[w][e] = ev; }
    m = fmaxf(m, ev);
  }
  m = wave_max(m);
  float ssum = 0.f;
  for (int e = lane; e < deg; e += 64) {
    float ev;
    if (e < MAXD) ev = lalpha[w][e];
    else { int s = edge_src[base + e]; ev = lrelu(asrc[s] + advv); }
    ssum += __expf(ev - m);
  }
  float inv = 1.f / (wave_sum(ssum) + 1e-16f);
  for (int e = lane; e < degc; e += 64) lalpha[w][e] = __expf(lalpha[w][e] - m) * inv;
  {
    int e = degc + lane;
    if (e < degp && e < MAXD) { lalpha[w][e] = 0.f; lsoff[w][e] = 0; }
  }

  int esub = lane / 20;
  int cg = lane - esub * 20;
  bool act = esub < 3;
  float ax = 0.f, ay = 0.f;
  const char* hb = (const char*)h2 + cg * 8;
  for (int i = 0; i < degp; i += 3) {
    if (act) {
      int slot = i + esub;
      float a = lalpha[w][slot];
      int so = lsoff[w][slot];
      float2 hv = *(const float2*)(hb + so);
      ax += a * hv.x; ay += a * hv.y;
    }
  }
  for (int e = MAXD + esub; e < deg; e += 3) {
    if (act) {
      int s = edge_src[base + e];
      float a = __expf(lrelu(asrc[s] + advv) - m) * inv;
      float2 hv = *(const float2*)(hb + (size_t)s * (NCLS * 4));
      ax += a * hv.x; ay += a * hv.y;
    }
  }
  float ax1 = __shfl(ax, lane + 20), ax2 = __shfl(ax, lane + 40);
  float ay1 = __shfl(ay, lane + 20), ay2 = __shfl(ay, lane + 40);
  float v0 = -INFINITY, v1 = -INFINITY;
  if (lane < 20) {
    v0 = ax + ax1 + ax2 + b2[2 * cg];
    v1 = ay + ay1 + ay2 + b2[2 * cg + 1];
  }
  float m2 = wave_max(fmaxf(v0, v1));
  float se = wave_sum(lane < 20 ? __expf(v0 - m2) + __expf(v1 - m2) : 0.f);
  if (lane < 20) {
    float ls = logf(se);
    *(float2*)&out[(size_t)n * NCLS + 2 * cg] = make_float2(v0 - m2 - ls, v1 - m2 - ls);
  }
}

extern "C" void kernel_launch(void* const* d_in, const int* in_sizes, int n_in,
                              void* d_out, int out_size, void* d_ws, size_t ws_size,
                              hipStream_t stream) {
  const float* x   = (const float*)d_in[0];
  const int*   ei  = (const int*)d_in[1];
  const float* W1  = (const float*)d_in[2];
  const float* as1 = (const float*)d_in[3];
  const float* ad1 = (const float*)d_in[4];
  const float* b1  = (const float*)d_in[5];
  const float* W2  = (const float*)d_in[6];
  const float* as2 = (const float*)d_in[7];
  const float* ad2 = (const float*)d_in[8];
  const float* b2  = (const float*)d_in[9];
  float* out = (float*)d_out;

  char* ws = (char*)d_ws;
  size_t off = 0;
  auto alloc = [&](size_t bytes) -> char* {
    char* p = ws + off;
    off += (bytes + 255) & ~(size_t)255;
    return p;
  };
  int* deg      = (int*)alloc((size_t)N_NODES * 4);
  int* cursor   = (int*)alloc((size_t)N_NODES * 4);
  int* offsets  = (int*)alloc((size_t)(N_NODES + 1) * 4);
  int* edge_src = (int*)alloc((size_t)EP * 4);
  unsigned short* xb    = (unsigned short*)alloc((size_t)MPAD * F_IN * 2);
  unsigned short* wb1t  = (unsigned short*)alloc((size_t)D1 * F_IN * 2);
  unsigned short* wb2t  = (unsigned short*)alloc((size_t)48 * D1 * 2);
  unsigned short* h1b   = (unsigned short*)alloc((size_t)N_NODES * D1 * 2);
  unsigned short* out1b = (unsigned short*)alloc((size_t)MPAD * D1 * 2);
  float* asrc1  = (float*)alloc((size_t)N_NODES * H1 * 4);
  float* adst1  = (float*)alloc((size_t)N_NODES * H1 * 4);
  float* h2     = (float*)alloc((size_t)N_NODES * NCLS * 4);
  float* asrc2  = (float*)alloc((size_t)N_NODES * 4);
  float* adst2  = (float*)alloc((size_t)N_NODES * 4);

  prep_kernel<<<PB_PAD, 256, 0, stream>>>(x, W1, W2, xb, wb1t, wb2t, deg, cursor, out1b);
  count_deg<<<(EP + 255) / 256, 256, 0, stream>>>(ei, deg);
  scan_kernel<<<1, SCAN_T, 0, stream>>>(deg, offsets);
  scatter_edges<<<(EP + 255) / 256, 256, 0, stream>>>(ei, offsets, cursor, edge_src);

  gemm1_mfma<<<157 * 4, 256, 0, stream>>>(xb, wb1t, as1, ad1, h1b, asrc1, adst1);
  agg1_kernel<<<N_NODES, 128, 0, stream>>>(offsets, edge_src, asrc1, adst1, h1b, b1, out1b);

  gemm2_mfma<<<157, 256, 0, stream>>>(out1b, wb2t, as2, ad2, h2, asrc2, adst2);
  agg2_kernel<<<N_NODES / 4, 256, 0, stream>>>(offsets, edge_src, asrc2, adst2, h2, b2, out);
}

// Round 7
// 159.320 us; speedup vs baseline: 1.4760x; 1.0832x over previous
//
#include <hip/hip_runtime.h>
#include <hip/hip_bf16.h>
#include <math.h>

#define N_NODES 20000
#define MPAD 20096               // 157*128
#define N_EDGES 320000
#define EP (N_EDGES + N_NODES)   // 340000
#define F_IN 256
#define NHID 64
#define H1 8
#define D1 512
#define NCLS 40
#define NEG_SLOPE 0.2f
#define MAXD 128                 // LDS-cached edges per dst; deg~Poisson(17)

typedef __attribute__((ext_vector_type(8))) short bf16x8;
typedef __attribute__((ext_vector_type(4))) float f32x4;

__device__ __forceinline__ float wave_max(float v) {
#pragma unroll
  for (int o = 32; o > 0; o >>= 1) v = fmaxf(v, __shfl_xor(v, o));
  return v;
}
__device__ __forceinline__ float wave_sum(float v) {
#pragma unroll
  for (int o = 32; o > 0; o >>= 1) v += __shfl_xor(v, o);
  return v;
}
__device__ __forceinline__ float bf2f(unsigned short u) {
  union { unsigned int i; float f; } c; c.i = ((unsigned int)u) << 16; return c.f;
}
__device__ __forceinline__ unsigned short f2bf(float f) {
  union { float f; unsigned int i; } c; c.f = f;
  unsigned int x = c.i;
  return (unsigned short)((x + 0x7fffu + ((x >> 16) & 1u)) >> 16);  // RNE
}
__device__ __forceinline__ float asf(unsigned int u) {
  union { unsigned int i; float f; } c; c.i = u; return c.f;
}
__device__ __forceinline__ float lrelu(float x) { return x > 0.f ? x : NEG_SLOPE * x; }

__device__ __forceinline__ void gload16(const void* g, void* l) {
  __builtin_amdgcn_global_load_lds((const __attribute__((address_space(1))) void*)g,
                                   (__attribute__((address_space(3))) void*)l, 16, 0, 0);
}

// ---------------- fused prep: convert_x | transpose_w1 | transpose_w2 | zero deg/cursor | zero pad ----------------
#define PB_CONV 2512             // MPAD*F_IN/8/256
#define PB_TW1  (PB_CONV + 32)
#define PB_TW2  (PB_TW1 + 96)    // 48*512/256
#define PB_ZERO (PB_TW2 + 157)   // 40000 ints
#define PB_PAD  (PB_ZERO + 24)   // 96*512 bf16 = 98304B = 6144*16B
__global__ __launch_bounds__(256) void prep_kernel(const float* __restrict__ x,
                                                   const float* __restrict__ W1,
                                                   const float* __restrict__ W2,
                                                   unsigned short* __restrict__ xb,
                                                   unsigned short* __restrict__ wb1t,
                                                   unsigned short* __restrict__ wb2t,
                                                   int* __restrict__ deg,
                                                   int* __restrict__ cursor,
                                                   unsigned short* __restrict__ out1b) {
  __shared__ float tsh[64][65];
  int bid = blockIdx.x;
  int t = threadIdx.x;
  if (bid < PB_CONV) {
    size_t base = ((size_t)bid * 256 + t) * 8;
    int row = (int)(base >> 8);
    ushort4 o0, o1;
    if (row < N_NODES) {
      float4 v0 = *(const float4*)&x[base];
      float4 v1 = *(const float4*)&x[base + 4];
      o0 = make_ushort4(f2bf(v0.x), f2bf(v0.y), f2bf(v0.z), f2bf(v0.w));
      o1 = make_ushort4(f2bf(v1.x), f2bf(v1.y), f2bf(v1.z), f2bf(v1.w));
    } else {
      o0 = make_ushort4(0, 0, 0, 0); o1 = o0;
    }
    *(ushort4*)&xb[base] = o0;
    *(ushort4*)&xb[base + 4] = o1;
  } else if (bid < PB_TW1) {
    int b2 = bid - PB_CONV;
    int bk = b2 & 3, bn = b2 >> 2;
    int tr = t >> 4, tc4 = (t & 15) * 4;
#pragma unroll
    for (int i = 0; i < 4; ++i) {
      int k = i * 16 + tr;
      float4 v = *(const float4*)&W1[(size_t)(bk * 64 + k) * D1 + bn * 64 + tc4];
      tsh[k][tc4] = v.x; tsh[k][tc4 + 1] = v.y; tsh[k][tc4 + 2] = v.z; tsh[k][tc4 + 3] = v.w;
    }
    __syncthreads();
#pragma unroll
    for (int i = 0; i < 4; ++i) {
      int n = i * 16 + tr;
      ushort4 o = make_ushort4(f2bf(tsh[tc4][n]), f2bf(tsh[tc4 + 1][n]),
                               f2bf(tsh[tc4 + 2][n]), f2bf(tsh[tc4 + 3][n]));
      *(ushort4*)&wb1t[(size_t)(bn * 64 + n) * F_IN + bk * 64 + tc4] = o;
    }
  } else if (bid < PB_TW2) {
    int idx = (bid - PB_TW1) * 256 + t;   // 0..24575 = c*512 + k
    int c = idx >> 9, k = idx & 511;
    wb2t[idx] = f2bf((c < NCLS) ? W2[(size_t)k * NCLS + c] : 0.f);
  } else if (bid < PB_ZERO) {
    int idx = (bid - PB_TW2) * 256 + t;
    if (idx < N_NODES) deg[idx] = 0;
    else if (idx < 2 * N_NODES) cursor[idx - N_NODES] = 0;
  } else {
    int idx = (bid - PB_ZERO) * 256 + t;  // 0..6143, 16B each
    uint4 z = make_uint4(0, 0, 0, 0);
    *(uint4*)((char*)out1b + (size_t)N_NODES * D1 * 2 + (size_t)idx * 16) = z;
  }
}

// ---------------- CSR build ----------------
__global__ void count_deg(const int* __restrict__ ei, int* __restrict__ deg) {
  int e = blockIdx.x * blockDim.x + threadIdx.x;
  if (e >= EP) return;
  int dst = (e < N_EDGES) ? ei[N_EDGES + e] : (e - N_EDGES);
  atomicAdd(&deg[dst], 1);
}

#define SCAN_T 1024
#define SCAN_CHUNK 20            // 1024*20 = 20480 >= 20000
__global__ __launch_bounds__(1024) void scan_kernel(const int* __restrict__ deg,
                                                    int* __restrict__ offsets) {
  __shared__ int wsum[16];
  int t = threadIdx.x;
  int w = t >> 6, lane = t & 63;
  int lo = t * SCAN_CHUNK;
  int hi = min(lo + SCAN_CHUNK, N_NODES);
  int s = 0;
  for (int i = lo; i < hi; ++i) s += deg[i];
  // inclusive scan within wave
  int incl = s;
#pragma unroll
  for (int o = 1; o < 64; o <<= 1) {
    int v = __shfl_up(incl, o);
    if (lane >= o) incl += v;
  }
  if (lane == 63) wsum[w] = incl;
  __syncthreads();
  if (t == 0) {
    int run = 0;
#pragma unroll
    for (int i = 0; i < 16; ++i) { int v = wsum[i]; wsum[i] = run; run += v; }
  }
  __syncthreads();
  int off = wsum[w] + incl - s;   // exclusive prefix for this thread
  for (int i = lo; i < hi; ++i) { offsets[i] = off; off += deg[i]; }
  if (hi == N_NODES && lo < N_NODES) offsets[N_NODES] = off;
}

__global__ void scatter_edges(const int* __restrict__ ei, const int* __restrict__ offsets,
                              int* __restrict__ cursor, int* __restrict__ edge_src) {
  int e = blockIdx.x * blockDim.x + threadIdx.x;
  if (e >= EP) return;
  int src, dst;
  if (e < N_EDGES) { src = ei[e]; dst = ei[N_EDGES + e]; }
  else             { src = dst = e - N_EDGES; }
  int pos = offsets[dst] + atomicAdd(&cursor[dst], 1);
  edge_src[pos] = src;
}

// ---------------- GEMM1 (MFMA): h1b = xb @ W1, fused alpha1. BK=64, 4 K-steps ----------------
__global__ __launch_bounds__(256) void gemm1_mfma(const unsigned short* __restrict__ xb,
                                                  const unsigned short* __restrict__ wb1t,
                                                  const float* __restrict__ a_src,
                                                  const float* __restrict__ a_dst,
                                                  unsigned short* __restrict__ h1b,
                                                  float* __restrict__ asrc,
                                                  float* __restrict__ adst) {
  __shared__ unsigned short As[128 * 64];   // 16KB, row = 8 chunks of 16B
  __shared__ unsigned short Bs[128 * 64];
  int tid = threadIdx.x;
  int w = tid >> 6, lane = tid & 63;
  int bn = blockIdx.x & 3, bm = blockIdx.x >> 2;
  int row0 = bm * 128, col0 = bn * 128;
  int wr = w >> 1, wc = w & 1;
  int cl = lane & 15, hi = lane >> 4;
  f32x4 acc[4][4] = {};
  for (int k0 = 0; k0 < F_IN; k0 += 64) {
#pragma unroll
    for (int c = 0; c < 4; ++c) {
      int slot = c * 256 + tid;
      int r = slot >> 3;
      int q = (slot & 7) ^ (r & 7);   // pre-swizzled source (rule 21); XOR key r&7
      gload16(xb + (size_t)(row0 + r) * F_IN + k0 + q * 8, (char*)As + (c * 256 + w * 64) * 16);
      gload16(wb1t + (size_t)(col0 + r) * F_IN + k0 + q * 8, (char*)Bs + (c * 256 + w * 64) * 16);
    }
    __syncthreads();
#pragma unroll
    for (int kk = 0; kk < 2; ++kk) {
      bf16x8 a[4], b[4];
#pragma unroll
      for (int m = 0; m < 4; ++m) {
        int r = wr * 64 + m * 16 + cl;
        a[m] = *(const bf16x8*)&As[r * 64 + ((((kk * 4 + hi)) ^ (r & 7)) << 3)];
      }
#pragma unroll
      for (int n = 0; n < 4; ++n) {
        int r = wc * 64 + n * 16 + cl;
        b[n] = *(const bf16x8*)&Bs[r * 64 + ((((kk * 4 + hi)) ^ (r & 7)) << 3)];
      }
#pragma unroll
      for (int m = 0; m < 4; ++m)
#pragma unroll
        for (int n = 0; n < 4; ++n)
          acc[m][n] = __builtin_amdgcn_mfma_f32_16x16x32_bf16(a[m], b[n], acc[m][n], 0, 0, 0);
    }
    __syncthreads();
  }
  int head = bn * 2 + wc;
  float asv[4], adv[4];
#pragma unroll
  for (int n = 0; n < 4; ++n) {
    asv[n] = a_src[head * 64 + n * 16 + cl];
    adv[n] = a_dst[head * 64 + n * 16 + cl];
  }
#pragma unroll
  for (int m = 0; m < 4; ++m) {
#pragma unroll
    for (int r = 0; r < 4; ++r) {
      int grow = row0 + wr * 64 + m * 16 + hi * 4 + r;
      float ps = acc[m][0][r] * asv[0] + acc[m][1][r] * asv[1] +
                 acc[m][2][r] * asv[2] + acc[m][3][r] * asv[3];
      float pd = acc[m][0][r] * adv[0] + acc[m][1][r] * adv[1] +
                 acc[m][2][r] * adv[2] + acc[m][3][r] * adv[3];
#pragma unroll
      for (int o = 8; o > 0; o >>= 1) { ps += __shfl_xor(ps, o); pd += __shfl_xor(pd, o); }
      if (grow < N_NODES) {
#pragma unroll
        for (int n = 0; n < 4; ++n)
          h1b[(size_t)grow * D1 + col0 + wc * 64 + n * 16 + cl] = f2bf(acc[m][n][r]);
        if (cl == 0) { asrc[grow * H1 + head] = ps; adst[grow * H1 + head] = pd; }
      }
    }
  }
}

// ---------------- agg1: 128-thr/node; (edge,head)-parallel softmax + full-row gather (unroll x2) ----------------
__global__ __launch_bounds__(128) void agg1_kernel(const int* __restrict__ offsets,
                                                   const int* __restrict__ edge_src,
                                                   const float* __restrict__ asrc,
                                                   const float* __restrict__ adst,
                                                   const unsigned short* __restrict__ h1b,
                                                   const float* __restrict__ b1,
                                                   unsigned short* __restrict__ out1b) {
  __shared__ float alphaT[MAXD][H1 + 1];
  __shared__ int   lsoff[MAXD];
  __shared__ float red[2][8];
  __shared__ float minv[2][8];
  __shared__ float accs[2][D1];
  int n = blockIdx.x;
  int t = threadIdx.x;
  int w = t >> 6, lane = t & 63;
  int base = offsets[n];
  int deg = offsets[n + 1] - base;
  int degc = min(deg, MAXD);

  for (int e = t; e < degc; e += 128) lsoff[e] = edge_src[base + e] << 10;
  __syncthreads();

  // softmax: thread = (edge et, head h); 16 edges x 8 heads per iteration
  int h = t & 7;
  int et = t >> 3;
  float advv = adst[n * H1 + h];
  float m = -INFINITY;
  for (int e = et; e < degc; e += 16) {
    int s = lsoff[e] >> 10;
    float ev = lrelu(asrc[s * H1 + h] + advv);
    alphaT[e][h] = ev;
    m = fmaxf(m, ev);
  }
  for (int e = MAXD + et; e < deg; e += 16)   // guard, never runs for this graph
    m = fmaxf(m, lrelu(asrc[edge_src[base + e] * H1 + h] + advv));
  m = fmaxf(m, __shfl_xor(m, 8));
  m = fmaxf(m, __shfl_xor(m, 16));
  m = fmaxf(m, __shfl_xor(m, 32));
  if (lane < 8) red[w][lane] = m;
  __syncthreads();
  m = fmaxf(red[0][h], red[1][h]);
  float ss = 0.f;
  for (int e = et; e < degc; e += 16) ss += __expf(alphaT[e][h] - m);
  for (int e = MAXD + et; e < deg; e += 16)
    ss += __expf(lrelu(asrc[edge_src[base + e] * H1 + h] + advv) - m);
  ss += __shfl_xor(ss, 8);
  ss += __shfl_xor(ss, 16);
  ss += __shfl_xor(ss, 32);
  __syncthreads();              // everyone done reading red (max)
  if (lane < 8) red[w][lane] = ss;
  __syncthreads();
  float inv = 1.f / (red[0][h] + red[1][h] + 1e-16f);
  if (t < 8) { minv[0][t] = m; minv[1][t] = inv; }   // h==t for t<8
  for (int e = et; e < degc; e += 16)
    alphaT[e][h] = __expf(alphaT[e][h] - m) * inv;
  __syncthreads();

  // gather: wave w handles edges w, w+2, ...; unroll x2 (two rows in flight)
  int myh = lane >> 3;
  const char* hb = (const char*)h1b + lane * 16;
  float acc[8] = {};
  int e = w;
  for (; e + 2 < degc; e += 4) {
    float a0 = alphaT[e][myh];
    float a1 = alphaT[e + 2][myh];
    uint4 u0 = *(const uint4*)(hb + lsoff[e]);
    uint4 u1 = *(const uint4*)(hb + lsoff[e + 2]);
#pragma unroll
    for (int j = 0; j < 4; ++j) {
      unsigned int x0 = ((const unsigned int*)&u0)[j];
      unsigned int x1 = ((const unsigned int*)&u1)[j];
      acc[2 * j]     += a0 * asf(x0 << 16);
      acc[2 * j + 1] += a0 * asf(x0 & 0xffff0000u);
      acc[2 * j]     += a1 * asf(x1 << 16);
      acc[2 * j + 1] += a1 * asf(x1 & 0xffff0000u);
    }
  }
  for (; e < degc; e += 2) {
    float a = alphaT[e][myh];
    uint4 uv = *(const uint4*)(hb + lsoff[e]);
#pragma unroll
    for (int j = 0; j < 4; ++j) {
      unsigned int u = ((const unsigned int*)&uv)[j];
      acc[2 * j]     += a * asf(u << 16);
      acc[2 * j + 1] += a * asf(u & 0xffff0000u);
    }
  }
  if (deg > MAXD) {             // guard, never runs for this graph
    float mh = minv[0][myh], invh = minv[1][myh];
    float advh = adst[n * H1 + myh];
    for (int e2 = MAXD + w; e2 < deg; e2 += 2) {
      int s = edge_src[base + e2];
      float a = __expf(lrelu(asrc[s * H1 + myh] + advh) - mh) * invh;
      uint4 uv = *(const uint4*)(hb + ((size_t)s << 10));
#pragma unroll
      for (int j = 0; j < 4; ++j) {
        unsigned int u = ((const unsigned int*)&uv)[j];
        acc[2 * j]     += a * asf(u << 16);
        acc[2 * j + 1] += a * asf(u & 0xffff0000u);
      }
    }
  }
  *(float4*)&accs[w][lane * 8]     = make_float4(acc[0], acc[1], acc[2], acc[3]);
  *(float4*)&accs[w][lane * 8 + 4] = make_float4(acc[4], acc[5], acc[6], acc[7]);
  __syncthreads();

  // reduce: thread t owns channels [4t, 4t+4)
  int c0 = t * 4;
  float4 s0 = *(float4*)&accs[0][c0];
  float4 s1 = *(float4*)&accs[1][c0];
  float4 bv = *(const float4*)&b1[c0];
  float v0 = s0.x + s1.x + bv.x, v1 = s0.y + s1.y + bv.y;
  float v2 = s0.z + s1.z + bv.z, v3 = s0.w + s1.w + bv.w;
  v0 = v0 > 0.f ? v0 : (__expf(v0) - 1.f);
  v1 = v1 > 0.f ? v1 : (__expf(v1) - 1.f);
  v2 = v2 > 0.f ? v2 : (__expf(v2) - 1.f);
  v3 = v3 > 0.f ? v3 : (__expf(v3) - 1.f);
  ushort4 o = make_ushort4(f2bf(v0), f2bf(v1), f2bf(v2), f2bf(v3));
  *(ushort4*)&out1b[(size_t)n * D1 + c0] = o;
}

// ---------------- GEMM2 (MFMA): h2 = out1b @ W2 (+pad), fused alpha2. BM=64, BK=64 ----------------
__global__ __launch_bounds__(256) void gemm2_mfma(const unsigned short* __restrict__ ab,
                                                  const unsigned short* __restrict__ wb2t,
                                                  const float* __restrict__ a_src2,
                                                  const float* __restrict__ a_dst2,
                                                  float* __restrict__ h2,
                                                  float* __restrict__ asrc,
                                                  float* __restrict__ adst) {
  __shared__ unsigned short As[64 * 64];   // 8KB
  __shared__ unsigned short Bs[48 * 64];   // 6KB
  int tid = threadIdx.x;
  int w = tid >> 6, lane = tid & 63;
  int row0 = blockIdx.x * 64;
  int cl = lane & 15, hi = lane >> 4;
  f32x4 acc[3] = {};
  for (int k0 = 0; k0 < D1; k0 += 64) {   // 8 K-steps
#pragma unroll
    for (int c = 0; c < 2; ++c) {
      int slot = c * 256 + tid;
      int r = slot >> 3;
      int q = (slot & 7) ^ (r & 7);
      gload16(ab + (size_t)(row0 + r) * D1 + k0 + q * 8, (char*)As + (c * 256 + w * 64) * 16);
    }
    {
      int r = tid >> 3;
      int q = (tid & 7) ^ (r & 7);
      gload16(wb2t + (size_t)r * D1 + k0 + q * 8, (char*)Bs + (w * 64) * 16);
      if (tid < 128) {
        int slot2 = 256 + tid;
        int r2 = slot2 >> 3;
        int q2 = (slot2 & 7) ^ (r2 & 7);
        gload16(wb2t + (size_t)r2 * D1 + k0 + q2 * 8, (char*)Bs + ((256 + w * 64)) * 16);
      }
    }
    __syncthreads();
#pragma unroll
    for (int kk = 0; kk < 2; ++kk) {
      int ra = w * 16 + cl;
      bf16x8 a = *(const bf16x8*)&As[ra * 64 + (((kk * 4 + hi) ^ (ra & 7)) << 3)];
#pragma unroll
      for (int n = 0; n < 3; ++n) {
        int rb = n * 16 + cl;
        bf16x8 b = *(const bf16x8*)&Bs[rb * 64 + (((kk * 4 + hi) ^ (rb & 7)) << 3)];
        acc[n] = __builtin_amdgcn_mfma_f32_16x16x32_bf16(a, b, acc[n], 0, 0, 0);
      }
    }
    __syncthreads();
  }
  float asv[3], adv[3];
#pragma unroll
  for (int n = 0; n < 3; ++n) {
    int c = n * 16 + cl;
    asv[n] = (c < NCLS) ? a_src2[c] : 0.f;
    adv[n] = (c < NCLS) ? a_dst2[c] : 0.f;
  }
#pragma unroll
  for (int r = 0; r < 4; ++r) {
    int grow = row0 + w * 16 + hi * 4 + r;
    float ps = acc[0][r] * asv[0] + acc[1][r] * asv[1] + acc[2][r] * asv[2];
    float pd = acc[0][r] * adv[0] + acc[1][r] * adv[1] + acc[2][r] * adv[2];
#pragma unroll
    for (int o = 8; o > 0; o >>= 1) { ps += __shfl_xor(ps, o); pd += __shfl_xor(pd, o); }
    if (grow < N_NODES) {
#pragma unroll
      for (int n = 0; n < 3; ++n) {
        int c = n * 16 + cl;
        if (c < NCLS) h2[(size_t)grow * NCLS + c] = acc[n][r];
      }
      if (cl == 0) { asrc[grow] = ps; adst[grow] = pd; }
    }
  }
}

// ---------------- agg2: LDS alpha + f32x2 gather (3 edges/iter) + b2 + log_softmax ----------------
__global__ __launch_bounds__(256) void agg2_kernel(const int* __restrict__ offsets,
                                                   const int* __restrict__ edge_src,
                                                   const float* __restrict__ asrc,
                                                   const float* __restrict__ adst,
                                                   const float* __restrict__ h2,
                                                   const float* __restrict__ b2,
                                                   float* __restrict__ out) {
  __shared__ float lalpha[4][MAXD];
  __shared__ int   lsoff[4][MAXD];
  int w = threadIdx.x >> 6;
  int lane = threadIdx.x & 63;
  int n = blockIdx.x * 4 + w;
  int base = offsets[n];
  int deg = offsets[n + 1] - base;
  int degc = min(deg, MAXD);
  int degp = ((degc + 2) / 3) * 3;

  float advv = adst[n];
  float m = -INFINITY;
  for (int e = lane; e < deg; e += 64) {
    int s = edge_src[base + e];
    float ev = lrelu(asrc[s] + advv);
    if (e < MAXD) { lsoff[w][e] = s * (NCLS * 4); lalpha[w][e] = ev; }
    m = fmaxf(m, ev);
  }
  m = wave_max(m);
  float ssum = 0.f;
  for (int e = lane; e < deg; e += 64) {
    float ev;
    if (e < MAXD) ev = lalpha[w][e];
    else { int s = edge_src[base + e]; ev = lrelu(asrc[s] + advv); }
    ssum += __expf(ev - m);
  }
  float inv = 1.f / (wave_sum(ssum) + 1e-16f);
  for (int e = lane; e < degc; e += 64) lalpha[w][e] = __expf(lalpha[w][e] - m) * inv;
  {
    int e = degc + lane;
    if (e < degp && e < MAXD) { lalpha[w][e] = 0.f; lsoff[w][e] = 0; }
  }

  int esub = lane / 20;
  int cg = lane - esub * 20;
  bool act = esub < 3;
  float ax = 0.f, ay = 0.f;
  const char* hb = (const char*)h2 + cg * 8;
  for (int i = 0; i < degp; i += 3) {
    if (act) {
      int slot = i + esub;
      float a = lalpha[w][slot];
      int so = lsoff[w][slot];
      float2 hv = *(const float2*)(hb + so);
      ax += a * hv.x; ay += a * hv.y;
    }
  }
  for (int e = MAXD + esub; e < deg; e += 3) {
    if (act) {
      int s = edge_src[base + e];
      float a = __expf(lrelu(asrc[s] + advv) - m) * inv;
      float2 hv = *(const float2*)(hb + (size_t)s * (NCLS * 4));
      ax += a * hv.x; ay += a * hv.y;
    }
  }
  float ax1 = __shfl(ax, lane + 20), ax2 = __shfl(ax, lane + 40);
  float ay1 = __shfl(ay, lane + 20), ay2 = __shfl(ay, lane + 40);
  float v0 = -INFINITY, v1 = -INFINITY;
  if (lane < 20) {
    v0 = ax + ax1 + ax2 + b2[2 * cg];
    v1 = ay + ay1 + ay2 + b2[2 * cg + 1];
  }
  float m2 = wave_max(fmaxf(v0, v1));
  float se = wave_sum(lane < 20 ? __expf(v0 - m2) + __expf(v1 - m2) : 0.f);
  if (lane < 20) {
    float ls = logf(se);
    *(float2*)&out[(size_t)n * NCLS + 2 * cg] = make_float2(v0 - m2 - ls, v1 - m2 - ls);
  }
}

extern "C" void kernel_launch(void* const* d_in, const int* in_sizes, int n_in,
                              void* d_out, int out_size, void* d_ws, size_t ws_size,
                              hipStream_t stream) {
  const float* x   = (const float*)d_in[0];
  const int*   ei  = (const int*)d_in[1];
  const float* W1  = (const float*)d_in[2];
  const float* as1 = (const float*)d_in[3];
  const float* ad1 = (const float*)d_in[4];
  const float* b1  = (const float*)d_in[5];
  const float* W2  = (const float*)d_in[6];
  const float* as2 = (const float*)d_in[7];
  const float* ad2 = (const float*)d_in[8];
  const float* b2  = (const float*)d_in[9];
  float* out = (float*)d_out;

  char* ws = (char*)d_ws;
  size_t off = 0;
  auto alloc = [&](size_t bytes) -> char* {
    char* p = ws + off;
    off += (bytes + 255) & ~(size_t)255;
    return p;
  };
  int* deg      = (int*)alloc((size_t)N_NODES * 4);
  int* cursor   = (int*)alloc((size_t)N_NODES * 4);
  int* offsets  = (int*)alloc((size_t)(N_NODES + 1) * 4);
  int* edge_src = (int*)alloc((size_t)EP * 4);
  unsigned short* xb    = (unsigned short*)alloc((size_t)MPAD * F_IN * 2);
  unsigned short* wb1t  = (unsigned short*)alloc((size_t)D1 * F_IN * 2);
  unsigned short* wb2t  = (unsigned short*)alloc((size_t)48 * D1 * 2);
  unsigned short* h1b   = (unsigned short*)alloc((size_t)N_NODES * D1 * 2);
  unsigned short* out1b = (unsigned short*)alloc((size_t)MPAD * D1 * 2);
  float* asrc1  = (float*)alloc((size_t)N_NODES * H1 * 4);
  float* adst1  = (float*)alloc((size_t)N_NODES * H1 * 4);
  float* h2     = (float*)alloc((size_t)N_NODES * NCLS * 4);
  float* asrc2  = (float*)alloc((size_t)N_NODES * 4);
  float* adst2  = (float*)alloc((size_t)N_NODES * 4);

  prep_kernel<<<PB_PAD, 256, 0, stream>>>(x, W1, W2, xb, wb1t, wb2t, deg, cursor, out1b);
  count_deg<<<(EP + 255) / 256, 256, 0, stream>>>(ei, deg);
  scan_kernel<<<1, SCAN_T, 0, stream>>>(deg, offsets);
  scatter_edges<<<(EP + 255) / 256, 256, 0, stream>>>(ei, offsets, cursor, edge_src);

  gemm1_mfma<<<157 * 4, 256, 0, stream>>>(xb, wb1t, as1, ad1, h1b, asrc1, adst1);
  agg1_kernel<<<N_NODES, 128, 0, stream>>>(offsets, edge_src, asrc1, adst1, h1b, b1, out1b);

  gemm2_mfma<<<MPAD / 64, 256, 0, stream>>>(out1b, wb2t, as2, ad2, h2, asrc2, adst2);
  agg2_kernel<<<N_NODES / 4, 256, 0, stream>>>(offsets, edge_src, asrc2, adst2, h2, b2, out);
}